// Round 1
// baseline (302.203 us; speedup 1.0000x reference)
//
#include <hip/hip_runtime.h>

// xDeepFM CIN, fused 3-layer kernel for MI355X (gfx950).
// Formulation: per batch b, layer = GEMM  nxt_b (128x64) = W (128xIC) @ P_b (ICx64),
// P_b[j*32+z, k] = h[b,j,k]*inp[b,z,k].  f16 MFMA (32x32x16), fp32 accumulate.
// Each block handles 2 batch elements (shares W A-fragments), all 3 layers fused,
// intermediate h kept in LDS as f16.

typedef _Float16 f16;
typedef _Float16 f16x8 __attribute__((ext_vector_type(8)));
typedef float f32x16 __attribute__((ext_vector_type(16)));

__device__ __forceinline__ f32x16 zero16() {
    f32x16 v;
#pragma unroll
    for (int i = 0; i < 16; ++i) v[i] = 0.0f;
    return v;
}

// Convert W0 (128x1024), W1/W2 (128x2048) fp32 -> f16, row-major unchanged.
__global__ void __launch_bounds__(256)
prep_weights(const float* __restrict__ W0, const float* __restrict__ W1,
             const float* __restrict__ W2,
             f16* __restrict__ W0f, f16* __restrict__ W1f, f16* __restrict__ W2f)
{
    int i = blockIdx.x * 256 + threadIdx.x;   // grid = 1024 * 256 = 262144
    if (i < 131072) W0f[i] = (f16)W0[i];
    if (i < 262144) { W1f[i] = (f16)W1[i]; W2f[i] = (f16)W2[i]; }
}

// One layer for 2 batch elements.  Wave handles output rows [o0, o0+32), all 64 cols.
// MFMA A-layout: A[m=lane&31][k=(lane>>5)*8+i]  (W rows, consecutive c)
// MFMA B-layout: B[k=(lane>>5)*8+i][n=lane&31]  (P: ip_chunk * h scalar)
template <int HJ>
__device__ __forceinline__ void layer_pair(
    const f16* __restrict__ h0, const f16* __restrict__ h1,   // LDS h[j*64+k], j<HJ
    const f16* __restrict__ Wf, int o0, int t, int q,
    f16x8 ipA0, f16x8 ipA1, f16x8 ipA2, f16x8 ipA3,           // b0: (zb0,n0),(zb0,n32),(zb1,n0),(zb1,n32)
    f16x8 ipB0, f16x8 ipB1, f16x8 ipB2, f16x8 ipB3,           // b1: same
    f32x16& a00, f32x16& a01, f32x16& a10, f32x16& a11)
{
    constexpr int IC = HJ * 32;
    const f16* Arow = Wf + (o0 + t) * IC + q * 8;
    a00 = zero16(); a01 = zero16(); a10 = zero16(); a11 = zero16();
#pragma unroll 8
    for (int j = 0; j < HJ; ++j) {
        f16 ha0 = h0[j * 64 + t];          // h[j][n] for n = t
        f16 ha1 = h0[j * 64 + 32 + t];     // n = 32+t
        f16 hb0 = h1[j * 64 + t];
        f16 hb1 = h1[j * 64 + 32 + t];
        f16x8 w0 = *(const f16x8*)(Arow + j * 32);        // c = j*32 + zb0*16 + q*8
        f16x8 w1 = *(const f16x8*)(Arow + j * 32 + 16);   // zb = 1
        a00 = __builtin_amdgcn_mfma_f32_32x32x16_f16(w0, ipA0 * ha0, a00, 0, 0, 0);
        a01 = __builtin_amdgcn_mfma_f32_32x32x16_f16(w0, ipA1 * ha1, a01, 0, 0, 0);
        a10 = __builtin_amdgcn_mfma_f32_32x32x16_f16(w0, ipB0 * hb0, a10, 0, 0, 0);
        a11 = __builtin_amdgcn_mfma_f32_32x32x16_f16(w0, ipB1 * hb1, a11, 0, 0, 0);
        a00 = __builtin_amdgcn_mfma_f32_32x32x16_f16(w1, ipA2 * ha0, a00, 0, 0, 0);
        a01 = __builtin_amdgcn_mfma_f32_32x32x16_f16(w1, ipA3 * ha1, a01, 0, 0, 0);
        a10 = __builtin_amdgcn_mfma_f32_32x32x16_f16(w1, ipB2 * hb0, a10, 0, 0, 0);
        a11 = __builtin_amdgcn_mfma_f32_32x32x16_f16(w1, ipB3 * hb1, a11, 0, 0, 0);
    }
}

// C/D layout (32x32): col = lane&31, row = (reg&3) + 8*(reg>>2) + 4*(lane>>5)
__device__ __forceinline__ void epi_h(const f32x16& A0, const f32x16& A1,
                                      f16* __restrict__ hN, const float* __restrict__ bias,
                                      int o0, int t, int q)
{
#pragma unroll
    for (int r = 0; r < 16; ++r) {
        int row = (r & 3) + 8 * (r >> 2) + 4 * q;
        int o = o0 + row;
        float bv = bias[o];
        hN[o * 64 + t]      = (f16)(A0[r] + bv);
        hN[o * 64 + 32 + t] = (f16)(A1[r] + bv);
    }
}

__device__ __forceinline__ void epi_sum(const f32x16& A0, const f32x16& A1,
                                        float* __restrict__ dst, const float* __restrict__ bias,
                                        int o0, int t, int q)
{
#pragma unroll
    for (int r = 0; r < 16; ++r) {
        float v = A0[r] + A1[r];                 // both n-halves, this lane's column
        v += __shfl_xor(v, 16);
        v += __shfl_xor(v, 8);
        v += __shfl_xor(v, 4);
        v += __shfl_xor(v, 2);
        v += __shfl_xor(v, 1);
        if (t == 0) {
            int row = (r & 3) + 8 * (r >> 2) + 4 * q;
            int o = o0 + row;
            dst[o] = v + 64.0f * bias[o];        // sum_k (x + b) = sum + 64*b
        }
    }
}

__global__ void __launch_bounds__(256, 2)
cin_fused(const float* __restrict__ inp,
          const f16* __restrict__ W0f, const f16* __restrict__ W1f, const f16* __restrict__ W2f,
          const float* __restrict__ b0v, const float* __restrict__ b1v, const float* __restrict__ b2v,
          float* __restrict__ out)
{
    // inpS chunk layout: index ((zb*2+q2)*64 + k)*8 + i  holds inp[b][zb*16+q2*8+i][k]
    __shared__ alignas(16) f16 inpS[2][2048];
    __shared__ alignas(16) f16 hA[2][2048];   // layer0 h = inp, [j*64+k], j<32
    __shared__ alignas(16) f16 hB[2][4096];   // layer0 out h, j<64
    __shared__ alignas(16) f16 hC[2][4096];   // layer1 out h, j<64
    __shared__ float biasS[384];

    const int tid = threadIdx.x;
    const int b0i = blockIdx.x * 2;

    for (int idx = tid; idx < 384; idx += 256) {
        float v = (idx < 128) ? b0v[idx] : (idx < 256 ? b1v[idx - 128] : b2v[idx - 256]);
        biasS[idx] = v;
    }
#pragma unroll
    for (int bb = 0; bb < 2; ++bb) {
        const float* ib = inp + (size_t)(b0i + bb) * 2048;
        for (int idx = tid; idx < 2048; idx += 256) {
            int i  = idx & 7;
            int k  = (idx >> 3) & 63;
            int qq = (idx >> 9) & 1;
            int zb = idx >> 10;
            inpS[bb][idx] = (f16)ib[(zb * 16 + qq * 8 + i) * 64 + k];
            hA[bb][idx]   = (f16)ib[idx];
        }
    }
    __syncthreads();

    const int lane = tid & 63;
    const int w = tid >> 6;
    const int t = lane & 31;
    const int q = lane >> 5;
    const int o0 = w * 32;

    // Hoisted B-operand inp chunks (constant across j within a layer, and across layers)
    f16x8 ipA0 = *(const f16x8*)&inpS[0][((0 + q) * 64 + t) * 8];
    f16x8 ipA1 = *(const f16x8*)&inpS[0][((0 + q) * 64 + 32 + t) * 8];
    f16x8 ipA2 = *(const f16x8*)&inpS[0][((2 + q) * 64 + t) * 8];
    f16x8 ipA3 = *(const f16x8*)&inpS[0][((2 + q) * 64 + 32 + t) * 8];
    f16x8 ipB0 = *(const f16x8*)&inpS[1][((0 + q) * 64 + t) * 8];
    f16x8 ipB1 = *(const f16x8*)&inpS[1][((0 + q) * 64 + 32 + t) * 8];
    f16x8 ipB2 = *(const f16x8*)&inpS[1][((2 + q) * 64 + t) * 8];
    f16x8 ipB3 = *(const f16x8*)&inpS[1][((2 + q) * 64 + 32 + t) * 8];

    f32x16 a00, a01, a10, a11;
    float* out0 = out + (size_t)b0i * 256;
    float* out1 = out + (size_t)(b0i + 1) * 256;

    // ---- Layer 0: Hj=32, IC=1024 ----
    layer_pair<32>(hA[0], hA[1], W0f, o0, t, q,
                   ipA0, ipA1, ipA2, ipA3, ipB0, ipB1, ipB2, ipB3,
                   a00, a01, a10, a11);
    if (w < 2) {
        epi_h(a00, a01, hB[0], biasS, o0, t, q);
        epi_h(a10, a11, hB[1], biasS, o0, t, q);
    } else {
        epi_sum(a00, a01, out0 - 64, biasS, o0, t, q);   // cols 0..63 = rows 64..127
        epi_sum(a10, a11, out1 - 64, biasS, o0, t, q);
    }
    __syncthreads();

    // ---- Layer 1: Hj=64, IC=2048 ----
    layer_pair<64>(hB[0], hB[1], W1f, o0, t, q,
                   ipA0, ipA1, ipA2, ipA3, ipB0, ipB1, ipB2, ipB3,
                   a00, a01, a10, a11);
    if (w < 2) {
        epi_h(a00, a01, hC[0], biasS + 128, o0, t, q);
        epi_h(a10, a11, hC[1], biasS + 128, o0, t, q);
    } else {
        epi_sum(a00, a01, out0 + 0, biasS + 128, o0, t, q);  // cols 64..127: 64 + (o-64)
        epi_sum(a10, a11, out1 + 0, biasS + 128, o0, t, q);
    }
    __syncthreads();

    // ---- Layer 2: Hj=64, IC=2048, all rows -> output cols 128..255 ----
    layer_pair<64>(hC[0], hC[1], W2f, o0, t, q,
                   ipA0, ipA1, ipA2, ipA3, ipB0, ipB1, ipB2, ipB3,
                   a00, a01, a10, a11);
    epi_sum(a00, a01, out0 + 128, biasS + 256, o0, t, q);
    epi_sum(a10, a11, out1 + 128, biasS + 256, o0, t, q);
}

extern "C" void kernel_launch(void* const* d_in, const int* in_sizes, int n_in,
                              void* d_out, int out_size, void* d_ws, size_t ws_size,
                              hipStream_t stream)
{
    const float* inp = (const float*)d_in[0];
    const float* W0  = (const float*)d_in[1];
    const float* b0  = (const float*)d_in[2];
    const float* W1  = (const float*)d_in[3];
    const float* b1  = (const float*)d_in[4];
    const float* W2  = (const float*)d_in[5];
    const float* b2  = (const float*)d_in[6];
    float* out = (float*)d_out;

    f16* W0f = (f16*)d_ws;            // 131072 elems
    f16* W1f = W0f + 131072;          // 262144 elems
    f16* W2f = W1f + 262144;          // 262144 elems  (total 1.25 MB of ws)

    prep_weights<<<1024, 256, 0, stream>>>(W0, W1, W2, W0f, W1f, W2f);
    cin_fused<<<1024, 256, 0, stream>>>(inp, W0f, W1f, W2f, b0, b1, b2, out);
}

// Round 2
// 291.978 us; speedup vs baseline: 1.0350x; 1.0350x over previous
//
#include <hip/hip_runtime.h>

// xDeepFM CIN, fused 3-layer kernel for MI355X (gfx950).
// Per batch b, layer = GEMM  nxt_b (128x64) = W (128xIC) @ P_b (ICx64),
// P_b[j*32+z, k] = h[b,j,k]*inp[b,z,k].  f16 MFMA (32x32x16), fp32 accumulate.
// Each block handles 2 batch elements (shares W A-fragments), all 3 layers fused.
// Intermediate h kept in LDS TRANSPOSED (hT[k][j], stride padded) so the per-j
// broadcast scalars for 4 consecutive j are one ds_read_b64, and the ip
// B-fragments are contiguous f16x8 slices of the same buffer.

typedef _Float16 f16;
typedef _Float16 f16x4 __attribute__((ext_vector_type(4)));
typedef _Float16 f16x8 __attribute__((ext_vector_type(8)));
typedef float f32x16 __attribute__((ext_vector_type(16)));
typedef float f32x4 __attribute__((ext_vector_type(4)));

__device__ __forceinline__ f32x16 zero16() {
    f32x16 v;
#pragma unroll
    for (int i = 0; i < 16; ++i) v[i] = 0.0f;
    return v;
}

// fp32 -> f16 weight conversion, vectorized. Layout row-major unchanged.
// W0: 131072 elems, W1: 262144, W2: 262144. Total 655360 -> 163840 threads x4.
__global__ void __launch_bounds__(256)
prep_weights(const float* __restrict__ W0, const float* __restrict__ W1,
             const float* __restrict__ W2, f16* __restrict__ dst)
{
    int i = (blockIdx.x * 256 + threadIdx.x) * 4;   // grid = 640
    const float* src;
    int off;
    if (i < 131072)      { src = W0; off = i; }
    else if (i < 393216) { src = W1; off = i - 131072; }
    else                 { src = W2; off = i - 393216; }
    f32x4 v = *(const f32x4*)(src + off);
    f16x4 o;
    o[0] = (f16)v[0]; o[1] = (f16)v[1]; o[2] = (f16)v[2]; o[3] = (f16)v[3];
    *(f16x4*)(dst + i) = o;
}

// One layer for 2 batch elements. Wave handles output rows [o0, o0+32), all 64 cols.
// A-layout (32x32x16): A[m=lane&31][k=(lane>>5)*8+i]; B[k=(lane>>5)*8+i][n=lane&31].
// hT is transposed: hT[k*STR + j] = h[j][k].
template <int HJ, int STR>
__device__ __forceinline__ void layer_pairT(
    const f16* __restrict__ h0T, const f16* __restrict__ h1T,
    const f16* __restrict__ Wf, int o0, int t, int q,
    f16x8 ipA0, f16x8 ipA1, f16x8 ipA2, f16x8 ipA3,
    f16x8 ipB0, f16x8 ipB1, f16x8 ipB2, f16x8 ipB3,
    f32x16& a00, f32x16& a01, f32x16& a10, f32x16& a11)
{
    constexpr int IC = HJ * 32;
    const f16* Arow = Wf + (o0 + t) * IC + q * 8;
    const f16* p0 = h0T + t * STR;
    const f16* p1 = h0T + (32 + t) * STR;
    const f16* p2 = h1T + t * STR;
    const f16* p3 = h1T + (32 + t) * STR;
    a00 = zero16(); a01 = zero16(); a10 = zero16(); a11 = zero16();
#pragma unroll 2
    for (int jj = 0; jj < HJ; jj += 4) {
        f16x4 ha0 = *(const f16x4*)(p0 + jj);   // h[b0][jj..jj+3][t]
        f16x4 ha1 = *(const f16x4*)(p1 + jj);   // h[b0][jj..jj+3][32+t]
        f16x4 hb0 = *(const f16x4*)(p2 + jj);
        f16x4 hb1 = *(const f16x4*)(p3 + jj);
#pragma unroll
        for (int jr = 0; jr < 4; ++jr) {
            int j = jj + jr;
            f16x8 w0 = *(const f16x8*)(Arow + j * 32);        // z = 0..15 half (q-split)
            f16x8 w1 = *(const f16x8*)(Arow + j * 32 + 16);   // z = 16..31 half
            f16 sa0 = ha0[jr], sa1 = ha1[jr];
            f16 sb0 = hb0[jr], sb1 = hb1[jr];
            a00 = __builtin_amdgcn_mfma_f32_32x32x16_f16(w0, ipA0 * sa0, a00, 0, 0, 0);
            a00 = __builtin_amdgcn_mfma_f32_32x32x16_f16(w1, ipA2 * sa0, a00, 0, 0, 0);
            a01 = __builtin_amdgcn_mfma_f32_32x32x16_f16(w0, ipA1 * sa1, a01, 0, 0, 0);
            a01 = __builtin_amdgcn_mfma_f32_32x32x16_f16(w1, ipA3 * sa1, a01, 0, 0, 0);
            a10 = __builtin_amdgcn_mfma_f32_32x32x16_f16(w0, ipB0 * sb0, a10, 0, 0, 0);
            a10 = __builtin_amdgcn_mfma_f32_32x32x16_f16(w1, ipB2 * sb0, a10, 0, 0, 0);
            a11 = __builtin_amdgcn_mfma_f32_32x32x16_f16(w0, ipB1 * sb1, a11, 0, 0, 0);
            a11 = __builtin_amdgcn_mfma_f32_32x32x16_f16(w1, ipB3 * sb1, a11, 0, 0, 0);
        }
    }
}

// C/D layout (32x32): col = lane&31, row = (reg&3) + 8*(reg>>2) + 4*(lane>>5).
// Write transposed h: hT[k*68 + o], vectorized over the 4 consecutive rows per reg-group.
__device__ __forceinline__ void epi_hT(const f32x16& A0, const f32x16& A1,
                                       f16* __restrict__ hT, const float* __restrict__ bias,
                                       int o0, int t, int q)
{
#pragma unroll
    for (int g = 0; g < 4; ++g) {
        int ob = o0 + 8 * g + 4 * q;
        f16x4 v0, v1;
#pragma unroll
        for (int r2 = 0; r2 < 4; ++r2) {
            float bv = bias[ob + r2];
            v0[r2] = (f16)(A0[4 * g + r2] + bv);
            v1[r2] = (f16)(A1[4 * g + r2] + bv);
        }
        *(f16x4*)&hT[t * 68 + ob]        = v0;
        *(f16x4*)&hT[(32 + t) * 68 + ob] = v1;
    }
}

__device__ __forceinline__ void epi_sum(const f32x16& A0, const f32x16& A1,
                                        float* __restrict__ dst, const float* __restrict__ bias,
                                        int o0, int t, int q)
{
#pragma unroll
    for (int r = 0; r < 16; ++r) {
        float v = A0[r] + A1[r];                 // both n-halves, this lane's column
        v += __shfl_xor(v, 16);
        v += __shfl_xor(v, 8);
        v += __shfl_xor(v, 4);
        v += __shfl_xor(v, 2);
        v += __shfl_xor(v, 1);
        if (t == 0) {
            int row = (r & 3) + 8 * (r >> 2) + 4 * q;
            int o = o0 + row;
            dst[o] = v + 64.0f * bias[o];        // sum_k (x + b) = sum + 64*b
        }
    }
}

__global__ void __launch_bounds__(256, 3)
cin_fused(const float* __restrict__ inp,
          const f16* __restrict__ W0f, const f16* __restrict__ W1f, const f16* __restrict__ W2f,
          const float* __restrict__ b0v, const float* __restrict__ b1v, const float* __restrict__ b2v,
          float* __restrict__ out)
{
    // LDS map (36352 B total):
    //   [0,     17408) : hAT [2][64*36] (9216 B, layer-0 h transposed)  -- then reused as
    //                    hCT [2][64*68] (17408 B, layer-1 output h)
    //   [17408, 34816) : hBT [2][64*68] (layer-0 output h)
    //   [34816, 36352) : biasS float[384]
    __shared__ alignas(16) char smem[36352];
    f16* hAT = (f16*)smem;                 // stride 36, j<32
    f16* hCT = (f16*)smem;                 // stride 68, j<64 (aliases hAT after layer0)
    f16* hBT = (f16*)(smem + 17408);       // stride 68, j<64
    float* biasS = (float*)(smem + 34816);

    const int tid = threadIdx.x;
    const int b0i = blockIdx.x * 2;

    for (int idx = tid; idx < 384; idx += 256) {
        float v = (idx < 128) ? b0v[idx] : (idx < 256 ? b1v[idx - 128] : b2v[idx - 256]);
        biasS[idx] = v;
    }
#pragma unroll
    for (int bb = 0; bb < 2; ++bb) {
        const float* ib = inp + (size_t)(b0i + bb) * 2048;
        f16* hA = hAT + bb * 64 * 36;
        for (int idx = tid; idx < 2048; idx += 256) {
            int k = idx & 63;          // coalesced global read within j-row
            int j = idx >> 6;
            hA[k * 36 + j] = (f16)ib[j * 64 + k];
        }
    }
    __syncthreads();

    const int lane = tid & 63;
    const int w = tid >> 6;
    const int t = lane & 31;
    const int q = lane >> 5;
    const int o0 = w * 32;

    // ip B-fragments are contiguous slices of transposed h (= inp), z in [q*8, q*8+8):
    //   ipX0: k=t,    z=q*8..q*8+7     ipX2: k=t,    z=16+q*8..
    const f16* hA0 = hAT;
    const f16* hA1 = hAT + 64 * 36;
    f16x8 ipA0 = *(const f16x8*)&hA0[t * 36 + q * 8];
    f16x8 ipA1 = *(const f16x8*)&hA0[(32 + t) * 36 + q * 8];
    f16x8 ipA2 = *(const f16x8*)&hA0[t * 36 + 16 + q * 8];
    f16x8 ipA3 = *(const f16x8*)&hA0[(32 + t) * 36 + 16 + q * 8];
    f16x8 ipB0 = *(const f16x8*)&hA1[t * 36 + q * 8];
    f16x8 ipB1 = *(const f16x8*)&hA1[(32 + t) * 36 + q * 8];
    f16x8 ipB2 = *(const f16x8*)&hA1[t * 36 + 16 + q * 8];
    f16x8 ipB3 = *(const f16x8*)&hA1[(32 + t) * 36 + 16 + q * 8];

    f32x16 a00, a01, a10, a11;
    float* out0 = out + (size_t)b0i * 256;
    float* out1 = out + (size_t)(b0i + 1) * 256;

    // ---- Layer 0: Hj=32, IC=1024 ----
    layer_pairT<32, 36>(hA0, hA1, W0f, o0, t, q,
                        ipA0, ipA1, ipA2, ipA3, ipB0, ipB1, ipB2, ipB3,
                        a00, a01, a10, a11);
    if (w < 2) {
        epi_hT(a00, a01, hBT,            biasS, o0, t, q);
        epi_hT(a10, a11, hBT + 64 * 68,  biasS, o0, t, q);
    } else {
        epi_sum(a00, a01, out0 - 64, biasS, o0, t, q);   // rows 64..127 -> out cols 0..63
        epi_sum(a10, a11, out1 - 64, biasS, o0, t, q);
    }
    __syncthreads();

    // ---- Layer 1: Hj=64, IC=2048 ----  (epilogue writes hCT, aliasing dead hAT)
    layer_pairT<64, 68>(hBT, hBT + 64 * 68, W1f, o0, t, q,
                        ipA0, ipA1, ipA2, ipA3, ipB0, ipB1, ipB2, ipB3,
                        a00, a01, a10, a11);
    if (w < 2) {
        epi_hT(a00, a01, hCT,           biasS + 128, o0, t, q);
        epi_hT(a10, a11, hCT + 64 * 68, biasS + 128, o0, t, q);
    } else {
        epi_sum(a00, a01, out0, biasS + 128, o0, t, q);  // rows 64..127 -> out cols 64..127
        epi_sum(a10, a11, out1, biasS + 128, o0, t, q);
    }
    __syncthreads();

    // ---- Layer 2: Hj=64, IC=2048, all rows -> output cols 128..255 ----
    layer_pairT<64, 68>(hCT, hCT + 64 * 68, W2f, o0, t, q,
                        ipA0, ipA1, ipA2, ipA3, ipB0, ipB1, ipB2, ipB3,
                        a00, a01, a10, a11);
    epi_sum(a00, a01, out0 + 128, biasS + 256, o0, t, q);
    epi_sum(a10, a11, out1 + 128, biasS + 256, o0, t, q);
}

extern "C" void kernel_launch(void* const* d_in, const int* in_sizes, int n_in,
                              void* d_out, int out_size, void* d_ws, size_t ws_size,
                              hipStream_t stream)
{
    const float* inp = (const float*)d_in[0];
    const float* W0  = (const float*)d_in[1];
    const float* b0  = (const float*)d_in[2];
    const float* W1  = (const float*)d_in[3];
    const float* b1  = (const float*)d_in[4];
    const float* W2  = (const float*)d_in[5];
    const float* b2  = (const float*)d_in[6];
    float* out = (float*)d_out;

    f16* Wf = (f16*)d_ws;             // W0f @0, W1f @131072, W2f @393216 (1.25 MB)
    prep_weights<<<640, 256, 0, stream>>>(W0, W1, W2, Wf);
    cin_fused<<<1024, 256, 0, stream>>>(inp, Wf, Wf + 131072, Wf + 393216,
                                        b0, b1, b2, out);
}

// Round 3
// 241.441 us; speedup vs baseline: 1.2517x; 1.2093x over previous
//
#include <hip/hip_runtime.h>

// xDeepFM CIN, fused 3-layer kernel for MI355X (gfx950).
// Per batch b, layer = GEMM  nxt_b (128x64) = W (128xIC) @ P_b (ICx64),
// P_b[j*32+z, k] = h[b,j,k]*inp[b,z,k].  f16 MFMA (32x32x16), fp32 accumulate.
// Each block handles 4 batch elements (W A-fragments shared across all 4 ->
// 16 MFMAs per W-load pair), all 3 layers fused, h kept in LDS transposed.
// W loads are register-prefetched one j ahead (depth-1 software pipeline).

typedef _Float16 f16;
typedef _Float16 f16x4 __attribute__((ext_vector_type(4)));
typedef _Float16 f16x8 __attribute__((ext_vector_type(8)));
typedef float f32x16 __attribute__((ext_vector_type(16)));
typedef float f32x4 __attribute__((ext_vector_type(4)));

__device__ __forceinline__ f32x16 zero16() {
    f32x16 v;
#pragma unroll
    for (int i = 0; i < 16; ++i) v[i] = 0.0f;
    return v;
}

// fp32 -> f16 weight conversion, vectorized, layout unchanged.
// W0: 131072 elems, W1: 262144, W2: 262144 -> 163840 threads x4.
__global__ void __launch_bounds__(256)
prep_weights(const float* __restrict__ W0, const float* __restrict__ W1,
             const float* __restrict__ W2, f16* __restrict__ dst)
{
    int i = (blockIdx.x * 256 + threadIdx.x) * 4;   // grid = 640
    const float* src;
    int off;
    if (i < 131072)      { src = W0; off = i; }
    else if (i < 393216) { src = W1; off = i - 131072; }
    else                 { src = W2; off = i - 393216; }
    f32x4 v = *(const f32x4*)(src + off);
    f16x4 o;
    o[0] = (f16)v[0]; o[1] = (f16)v[1]; o[2] = (f16)v[2]; o[3] = (f16)v[3];
    *(f16x4*)(dst + i) = o;
}

// One layer, 4 batch elements. Wave handles output rows [o0,o0+32), all 64 cols.
// A-layout (32x32x16): A[m=lane&31][k=(lane>>5)*8+i]; B[k=(lane>>5)*8+i][n=lane&31].
// hT transposed: hT[k*STR + j] = h[j][k]; batch stride 64*STR.
template <int HJ, int STR>
__device__ __forceinline__ void layer_quad(
    const f16* __restrict__ hT, const f16* __restrict__ Wf,
    int o0, int t, int q, const f16x8 (&ip)[4][4], f32x16 (&acc)[4][2])
{
    constexpr int IC = HJ * 32;
    const f16* Arow = Wf + (o0 + t) * IC + q * 8;
#pragma unroll
    for (int b = 0; b < 4; ++b) { acc[b][0] = zero16(); acc[b][1] = zero16(); }

    f16x8 w0 = *(const f16x8*)(Arow);        // prefetch j = 0
    f16x8 w1 = *(const f16x8*)(Arow + 16);

    for (int jj = 0; jj < HJ; jj += 4) {
        f16x4 hs[4][2];
#pragma unroll
        for (int b = 0; b < 4; ++b) {
            hs[b][0] = *(const f16x4*)(hT + b * 64 * STR + t * STR + jj);
            hs[b][1] = *(const f16x4*)(hT + b * 64 * STR + (32 + t) * STR + jj);
        }
#pragma unroll
        for (int jr = 0; jr < 4; ++jr) {
            f16x8 cw0 = w0, cw1 = w1;
            int jn = jj + jr + 1;
            jn = jn < HJ ? jn : HJ - 1;      // clamped depth-1 prefetch, no branch
            w0 = *(const f16x8*)(Arow + jn * 32);
            w1 = *(const f16x8*)(Arow + jn * 32 + 16);
#pragma unroll
            for (int b = 0; b < 4; ++b) {
                f16 s0 = hs[b][0][jr], s1 = hs[b][1][jr];
                acc[b][0] = __builtin_amdgcn_mfma_f32_32x32x16_f16(cw0, ip[b][0] * s0, acc[b][0], 0, 0, 0);
                acc[b][1] = __builtin_amdgcn_mfma_f32_32x32x16_f16(cw0, ip[b][1] * s1, acc[b][1], 0, 0, 0);
                acc[b][0] = __builtin_amdgcn_mfma_f32_32x32x16_f16(cw1, ip[b][2] * s0, acc[b][0], 0, 0, 0);
                acc[b][1] = __builtin_amdgcn_mfma_f32_32x32x16_f16(cw1, ip[b][3] * s1, acc[b][1], 0, 0, 0);
            }
        }
    }
}

// C/D layout (32x32): col = lane&31, row = (reg&3) + 8*(reg>>2) + 4*(lane>>5).
// Write transposed h: hT[k*68 + o], vectorized (f16x4 over consecutive rows).
__device__ __forceinline__ void epi_hT(const f32x16& A0, const f32x16& A1,
                                       f16* __restrict__ hT, const float* __restrict__ bias,
                                       int o0, int t, int q)
{
#pragma unroll
    for (int g = 0; g < 4; ++g) {
        int ob = o0 + 8 * g + 4 * q;
        f16x4 v0, v1;
#pragma unroll
        for (int r2 = 0; r2 < 4; ++r2) {
            float bv = bias[ob + r2];
            v0[r2] = (f16)(A0[4 * g + r2] + bv);
            v1[r2] = (f16)(A1[4 * g + r2] + bv);
        }
        *(f16x4*)&hT[t * 68 + ob]        = v0;
        *(f16x4*)&hT[(32 + t) * 68 + ob] = v1;
    }
}

__device__ __forceinline__ void epi_sum(const f32x16& A0, const f32x16& A1,
                                        float* __restrict__ dst, const float* __restrict__ bias,
                                        int o0, int t, int q)
{
#pragma unroll
    for (int r = 0; r < 16; ++r) {
        float v = A0[r] + A1[r];                 // both n-halves, this lane's column
        v += __shfl_xor(v, 16);
        v += __shfl_xor(v, 8);
        v += __shfl_xor(v, 4);
        v += __shfl_xor(v, 2);
        v += __shfl_xor(v, 1);
        if (t == 0) {
            int row = (r & 3) + 8 * (r >> 2) + 4 * q;
            int o = o0 + row;
            dst[o] = v + 64.0f * bias[o];        // sum_k (x + b) = sum + 64*b
        }
    }
}

__global__ void __launch_bounds__(256, 2)
cin_fused(const float* __restrict__ inp,
          const f16* __restrict__ W0f, const f16* __restrict__ W1f, const f16* __restrict__ W2f,
          const float* __restrict__ b0v, const float* __restrict__ b1v, const float* __restrict__ b2v,
          float* __restrict__ out)
{
    // LDS map (71168 B):
    //   [0,     34816) : hAT [4][64*36] (18432 B used) -> reused as hCT [4][64*68]
    //   [34816, 69632) : hBT [4][64*68]
    //   [69632, 71168) : biasS float[384]
    __shared__ alignas(16) char smem[71168];
    f16* hAT = (f16*)smem;                 // stride 36, j<32
    f16* hCT = (f16*)smem;                 // stride 68, j<64 (aliases dead hAT)
    f16* hBT = (f16*)(smem + 34816);       // stride 68, j<64
    float* biasS = (float*)(smem + 69632);

    const int tid = threadIdx.x;
    const int b0i = blockIdx.x * 4;

    for (int idx = tid; idx < 384; idx += 256) {
        float v = (idx < 128) ? b0v[idx] : (idx < 256 ? b1v[idx - 128] : b2v[idx - 256]);
        biasS[idx] = v;
    }
#pragma unroll
    for (int bb = 0; bb < 4; ++bb) {
        const float* ib = inp + (size_t)(b0i + bb) * 2048;
        f16* hA = hAT + bb * 64 * 36;
        for (int idx = tid; idx < 2048; idx += 256) {
            int k = idx & 63;          // coalesced global read; transposed LDS write
            int j = idx >> 6;
            hA[k * 36 + j] = (f16)ib[idx];
        }
    }
    __syncthreads();

    const int lane = tid & 63;
    const int w = tid >> 6;
    const int t = lane & 31;
    const int q = lane >> 5;
    const int o0 = w * 32;

    // ip B-fragments: contiguous slices of transposed layer-0 h (= inp).
    f16x8 ip[4][4];
#pragma unroll
    for (int b = 0; b < 4; ++b) {
        const f16* hA = hAT + b * 64 * 36;
        ip[b][0] = *(const f16x8*)&hA[t * 36 + q * 8];
        ip[b][1] = *(const f16x8*)&hA[(32 + t) * 36 + q * 8];
        ip[b][2] = *(const f16x8*)&hA[t * 36 + 16 + q * 8];
        ip[b][3] = *(const f16x8*)&hA[(32 + t) * 36 + 16 + q * 8];
    }

    f32x16 acc[4][2];
    float* outp[4];
#pragma unroll
    for (int b = 0; b < 4; ++b) outp[b] = out + (size_t)(b0i + b) * 256;

    // ---- Layer 0: Hj=32, IC=1024 ----
    layer_quad<32, 36>(hAT, W0f, o0, t, q, ip, acc);
    if (w < 2) {
#pragma unroll
        for (int b = 0; b < 4; ++b)
            epi_hT(acc[b][0], acc[b][1], hBT + b * 64 * 68, biasS, o0, t, q);
    } else {
#pragma unroll
        for (int b = 0; b < 4; ++b)
            epi_sum(acc[b][0], acc[b][1], outp[b] - 64, biasS, o0, t, q); // rows 64..127 -> cols 0..63
    }
    __syncthreads();

    // ---- Layer 1: Hj=64, IC=2048 ----  (writes hCT over dead hAT region)
    layer_quad<64, 68>(hBT, W1f, o0, t, q, ip, acc);
    if (w < 2) {
#pragma unroll
        for (int b = 0; b < 4; ++b)
            epi_hT(acc[b][0], acc[b][1], hCT + b * 64 * 68, biasS + 128, o0, t, q);
    } else {
#pragma unroll
        for (int b = 0; b < 4; ++b)
            epi_sum(acc[b][0], acc[b][1], outp[b], biasS + 128, o0, t, q); // rows 64..127 -> cols 64..127
    }
    __syncthreads();

    // ---- Layer 2: Hj=64, IC=2048, all rows -> output cols 128..255 ----
    layer_quad<64, 68>(hCT, W2f, o0, t, q, ip, acc);
#pragma unroll
    for (int b = 0; b < 4; ++b)
        epi_sum(acc[b][0], acc[b][1], outp[b] + 128, biasS + 256, o0, t, q);
}

extern "C" void kernel_launch(void* const* d_in, const int* in_sizes, int n_in,
                              void* d_out, int out_size, void* d_ws, size_t ws_size,
                              hipStream_t stream)
{
    const float* inp = (const float*)d_in[0];
    const float* W0  = (const float*)d_in[1];
    const float* b0  = (const float*)d_in[2];
    const float* W1  = (const float*)d_in[3];
    const float* b1  = (const float*)d_in[4];
    const float* W2  = (const float*)d_in[5];
    const float* b2  = (const float*)d_in[6];
    float* out = (float*)d_out;

    f16* Wf = (f16*)d_ws;             // W0f @0, W1f @131072, W2f @393216 (1.25 MB)
    prep_weights<<<640, 256, 0, stream>>>(W0, W1, W2, Wf);
    cin_fused<<<512, 256, 0, stream>>>(inp, Wf, Wf + 131072, Wf + 393216,
                                       b0, b1, b2, out);
}

// Round 4
// 225.367 us; speedup vs baseline: 1.3409x; 1.0713x over previous
//
#include <hip/hip_runtime.h>

// xDeepFM CIN, fused 3-layer kernel for MI355X (gfx950) — algebraic restructure.
// Key identity: output cols only need sum_k nxt[o,k] = W_o @ p, p[c=j*32+z] =
// sum_k h[j,k]*inp[z,k].  So per layer: (a) tiny p-GEMM (HJx32, K=64),
// (b) h-GEMM only for rows 0..63 (layers 0,1), (c) batched o-GEMV (N=4 batches)
// against p.  3x fewer MFMA FLOPs than the full M=128 formulation.
// Wave <-> batch mapping: h-chain is wave-private (no barriers); only the
// cooperative o-GEMV (K split across 4 waves) uses pS/rS + 2 barriers/layer.

typedef _Float16 f16;
typedef _Float16 f16x4 __attribute__((ext_vector_type(4)));
typedef _Float16 f16x8 __attribute__((ext_vector_type(8)));
typedef float f32x4 __attribute__((ext_vector_type(4)));
typedef float f32x16 __attribute__((ext_vector_type(16)));

#define STR 72   // LDS row stride (f16) for inpP/hP: 144B = 9*16B -> b128-aligned rows

__device__ __forceinline__ f32x16 zero16() {
    f32x16 v;
#pragma unroll
    for (int i = 0; i < 16; ++i) v[i] = 0.0f;
    return v;
}
__device__ __forceinline__ f16x8 zero8h() {
    f16x8 v;
#pragma unroll
    for (int i = 0; i < 8; ++i) v[i] = (f16)0.0f;
    return v;
}

// fp32 -> f16 weight conversion, vectorized, layout unchanged.
__global__ void __launch_bounds__(256)
prep_weights(const float* __restrict__ W0, const float* __restrict__ W1,
             const float* __restrict__ W2, f16* __restrict__ dst)
{
    int i = (blockIdx.x * 256 + threadIdx.x) * 4;   // grid = 640
    const float* src;
    int off;
    if (i < 131072)      { src = W0; off = i; }
    else if (i < 393216) { src = W1; off = i - 131072; }
    else                 { src = W2; off = i - 393216; }
    f32x4 v = *(const f32x4*)(src + off);
    f16x4 o;
    o[0] = (f16)v[0]; o[1] = (f16)v[1]; o[2] = (f16)v[2]; o[3] = (f16)v[3];
    *(f16x4*)(dst + i) = o;
}

// p-GEMM: p[j,z] = sum_k h[j,k] inp[z,k].  M=HJ, N=32, K=64.
// A[m=j][k] from hsrc plain; B[k][n=z] from inpP plain. Result -> pSw (f16).
template <int HJ>
__device__ __forceinline__ void p_gemm(const f16* __restrict__ hsrc,
                                       const f16* __restrict__ inpP,
                                       f16* __restrict__ pSw, int t, int q)
{
    constexpr int MT = HJ / 32;
    f32x16 acc[MT];
#pragma unroll
    for (int m = 0; m < MT; ++m) acc[m] = zero16();
#pragma unroll
    for (int s = 0; s < 4; ++s) {
        int kc = s * 16 + q * 8;
        f16x8 b = *(const f16x8*)(inpP + t * STR + kc);       // inp[z=t][kc..]
#pragma unroll
        for (int m = 0; m < MT; ++m) {
            f16x8 a = *(const f16x8*)(hsrc + (m * 32 + t) * STR + kc);
            acc[m] = __builtin_amdgcn_mfma_f32_32x32x16_f16(a, b, acc[m], 0, 0, 0);
        }
    }
    // C/D: col = t = z, row = (r&3)+8*(r>>2)+4*q (+32*m) = j
#pragma unroll
    for (int m = 0; m < MT; ++m)
#pragma unroll
        for (int r = 0; r < 16; ++r) {
            int j = m * 32 + (r & 3) + 8 * (r >> 2) + 4 * q;
            pSw[j * 32 + t] = (f16)acc[m][r];
        }
}

// h-GEMM: nxt rows 0..63 for one batch.  M=64, N=64, K=HJ*32.
// ip[ks][nh][i] = inp[z=ks*16+q*8+i][k=nh*32+t]; B-frag = ip * h-scalar.
template <int HJ>
__device__ __forceinline__ void h_gemm(const f16* __restrict__ hsrc,
                                       const f16* __restrict__ Wl,
                                       int t, int q, const f16x8 (&ip)[2][2],
                                       f32x16 (&acc)[2][2])
{
    constexpr int IC = HJ * 32;
    const f16* A0 = Wl + t * IC + q * 8;           // Mt0 rows 0..31
    const f16* A1 = Wl + (32 + t) * IC + q * 8;    // Mt1 rows 32..63
#pragma unroll
    for (int m = 0; m < 2; ++m)
#pragma unroll
        for (int nh = 0; nh < 2; ++nh) acc[m][nh] = zero16();

    f16x8 w00 = *(const f16x8*)(A0);               // prefetch j=0
    f16x8 w01 = *(const f16x8*)(A0 + 16);
    f16x8 w10 = *(const f16x8*)(A1);
    f16x8 w11 = *(const f16x8*)(A1 + 16);

#pragma unroll 4
    for (int j = 0; j < HJ; ++j) {
        f16x8 c00 = w00, c01 = w01, c10 = w10, c11 = w11;
        int jn = j + 1 < HJ ? j + 1 : HJ - 1;      // clamped depth-1 prefetch
        w00 = *(const f16x8*)(A0 + jn * 32);
        w01 = *(const f16x8*)(A0 + jn * 32 + 16);
        w10 = *(const f16x8*)(A1 + jn * 32);
        w11 = *(const f16x8*)(A1 + jn * 32 + 16);

        f16 s0 = hsrc[j * STR + t];                // h[j][t]
        f16 s1 = hsrc[j * STR + 32 + t];           // h[j][32+t]
        f16x8 b00 = ip[0][0] * s0, b01 = ip[0][1] * s1;   // ks0
        f16x8 b10 = ip[1][0] * s0, b11 = ip[1][1] * s1;   // ks1
        acc[0][0] = __builtin_amdgcn_mfma_f32_32x32x16_f16(c00, b00, acc[0][0], 0, 0, 0);
        acc[0][1] = __builtin_amdgcn_mfma_f32_32x32x16_f16(c00, b01, acc[0][1], 0, 0, 0);
        acc[1][0] = __builtin_amdgcn_mfma_f32_32x32x16_f16(c10, b00, acc[1][0], 0, 0, 0);
        acc[1][1] = __builtin_amdgcn_mfma_f32_32x32x16_f16(c10, b01, acc[1][1], 0, 0, 0);
        acc[0][0] = __builtin_amdgcn_mfma_f32_32x32x16_f16(c01, b10, acc[0][0], 0, 0, 0);
        acc[0][1] = __builtin_amdgcn_mfma_f32_32x32x16_f16(c01, b11, acc[0][1], 0, 0, 0);
        acc[1][0] = __builtin_amdgcn_mfma_f32_32x32x16_f16(c11, b10, acc[1][0], 0, 0, 0);
        acc[1][1] = __builtin_amdgcn_mfma_f32_32x32x16_f16(c11, b11, acc[1][1], 0, 0, 0);
    }
}

// Write h_{l+1} = acc + bias into plain LDS (stride STR), rows 0..63.
__device__ __forceinline__ void epi_h(const f32x16 (&acc)[2][2], f16* __restrict__ hdst,
                                      const float* __restrict__ bl, int t, int q)
{
#pragma unroll
    for (int m = 0; m < 2; ++m)
#pragma unroll
        for (int r = 0; r < 16; ++r) {
            int row = m * 32 + (r & 3) + 8 * (r >> 2) + 4 * q;
            float bv = bl[row];
            hdst[row * STR + t]      = (f16)(acc[m][0][r] + bv);
            hdst[row * STR + 32 + t] = (f16)(acc[m][1][r] + bv);
        }
}

// Batched o-GEMV: D[o, b<4] = sum_c Wo[o,c] p_b[c].  K split across 4 waves,
// fp32 partials -> rS[o*16 + w*4 + b].
template <int ICN, int MT>
__device__ __forceinline__ void o_gemv(const f16* __restrict__ Wo,
                                       const f16* __restrict__ pS,
                                       float* __restrict__ rS,
                                       int w, int t, int q)
{
    f32x16 acc[MT];
#pragma unroll
    for (int m = 0; m < MT; ++m) acc[m] = zero16();
    const int wbase = w * (ICN / 4);
    const bool valid = t < 4;
    const f16* pbase = pS + (t & 3) * 2048;
    const f16x8 zf = zero8h();
#pragma unroll 4
    for (int s = 0; s < ICN / 64; ++s) {
        int c = wbase + s * 16 + q * 8;
        f16x8 b = *(const f16x8*)(pbase + c);
        b = valid ? b : zf;                        // zero cols n>=4
#pragma unroll
        for (int m = 0; m < MT; ++m) {
            f16x8 a = *(const f16x8*)(Wo + (m * 32 + t) * ICN + c);
            acc[m] = __builtin_amdgcn_mfma_f32_32x32x16_f16(a, b, acc[m], 0, 0, 0);
        }
    }
#pragma unroll
    for (int m = 0; m < MT; ++m)
#pragma unroll
        for (int r = 0; r < 16; ++r) {
            int o = m * 32 + (r & 3) + 8 * (r >> 2) + 4 * q;
            if (valid) rS[o * 16 + w * 4 + t] = acc[m][r];
        }
}

// Sum the 4 wave-partials, add 64*bias, store to out.
__device__ __forceinline__ void reduce_out(const float* __restrict__ rS,
                                           float* __restrict__ out, int b0i,
                                           int colbase, const float* __restrict__ biasv,
                                           int nOut, int tid)
{
    int b = tid & 3;
    for (int o = tid >> 2; o < nOut; o += 64) {
        float s = rS[o * 16 + b] + rS[o * 16 + 4 + b] +
                  rS[o * 16 + 8 + b] + rS[o * 16 + 12 + b];
        out[(size_t)(b0i + b) * 256 + colbase + o] = s + 64.0f * biasv[o];
    }
}

__global__ void __launch_bounds__(256, 2)
cin_fused(const float* __restrict__ inp,
          const f16* __restrict__ W0f, const f16* __restrict__ W1f, const f16* __restrict__ W2f,
          const float* __restrict__ b0v, const float* __restrict__ b1v, const float* __restrict__ b2v,
          float* __restrict__ out)
{
    // LDS map (79872 B):
    //   per-wave slot w (13824 B each): inpP [32][STR] (4608) + hP [64][STR] (9216)
    //   [55296, 71680): pS  f16 [4][2048]  (p vectors, shared)
    //   [71680, 79872): rS  f32 [128][16]  (o-GEMV partials, shared)
    __shared__ __attribute__((aligned(16))) char smem[79872];

    const int tid = threadIdx.x;
    const int w = tid >> 6;
    const int lane = tid & 63;
    const int t = lane & 31;
    const int q = lane >> 5;
    const int b0i = blockIdx.x * 4;

    f16* inpP = (f16*)(smem + w * 13824);
    f16* hP   = inpP + 32 * STR;
    f16* pS   = (f16*)(smem + 55296);
    f16* pSw  = pS + w * 2048;
    float* rS = (float*)(smem + 71680);

    // Stage this wave's batch: inp (f32, plain) -> inpP (f16, stride STR).
    const float* ib = inp + (size_t)(b0i + w) * 2048;
#pragma unroll
    for (int it = 0; it < 8; ++it) {
        int idx = it * 256 + lane * 4;
        f32x4 v = *(const f32x4*)(ib + idx);
        int z = idx >> 6, k = idx & 63;
        f16x4 h4;
        h4[0] = (f16)v[0]; h4[1] = (f16)v[1]; h4[2] = (f16)v[2]; h4[3] = (f16)v[3];
        *(f16x4*)(inpP + z * STR + k) = h4;
    }
    // (wave-private: no barrier needed)

    // ip fragments: ip[ks][nh][i] = inp[z=ks*16+q*8+i][k=nh*32+t]
    f16x8 ip[2][2];
#pragma unroll
    for (int ks = 0; ks < 2; ++ks)
#pragma unroll
        for (int nh = 0; nh < 2; ++nh) {
            f16x8 v;
#pragma unroll
            for (int i = 0; i < 8; ++i)
                v[i] = inpP[(ks * 16 + q * 8 + i) * STR + nh * 32 + t];
            ip[ks][nh] = v;
        }

    f32x16 hacc[2][2];

    // ---- Layer 0 (HJ=32, IC=1024) ----
    p_gemm<32>(inpP, inpP, pSw, t, q);
    h_gemm<32>(inpP, W0f, t, q, ip, hacc);
    epi_h(hacc, hP, b0v, t, q);
    __syncthreads();                                  // pS ready
    o_gemv<1024, 2>(W0f + 64 * 1024, pS, rS, w, t, q);
    __syncthreads();                                  // rS ready / pS free
    reduce_out(rS, out, b0i, 0, b0v + 64, 64, tid);

    // ---- Layer 1 (HJ=64, IC=2048) ----
    p_gemm<64>(hP, inpP, pSw, t, q);
    h_gemm<64>(hP, W1f, t, q, ip, hacc);
    epi_h(hacc, hP, b1v, t, q);                       // h2 overwrites h1 (same wave)
    __syncthreads();
    o_gemv<2048, 2>(W1f + 64 * 2048, pS, rS, w, t, q);
    __syncthreads();
    reduce_out(rS, out, b0i, 64, b1v + 64, 64, tid);

    // ---- Layer 2 (HJ=64, IC=2048, all 128 rows are output) ----
    p_gemm<64>(hP, inpP, pSw, t, q);
    __syncthreads();
    o_gemv<2048, 4>(W2f, pS, rS, w, t, q);
    __syncthreads();
    reduce_out(rS, out, b0i, 128, b2v, 128, tid);
}

extern "C" void kernel_launch(void* const* d_in, const int* in_sizes, int n_in,
                              void* d_out, int out_size, void* d_ws, size_t ws_size,
                              hipStream_t stream)
{
    const float* inp = (const float*)d_in[0];
    const float* W0  = (const float*)d_in[1];
    const float* b0  = (const float*)d_in[2];
    const float* W1  = (const float*)d_in[3];
    const float* b1  = (const float*)d_in[4];
    const float* W2  = (const float*)d_in[5];
    const float* b2  = (const float*)d_in[6];
    float* out = (float*)d_out;

    f16* Wf = (f16*)d_ws;             // W0f @0, W1f @131072, W2f @393216 (1.25 MB)
    prep_weights<<<640, 256, 0, stream>>>(W0, W1, W2, Wf);
    cin_fused<<<512, 256, 0, stream>>>(inp, Wf, Wf + 131072, Wf + 393216,
                                       b0, b1, b2, out);
}

// Round 5
// 169.655 us; speedup vs baseline: 1.7813x; 1.3284x over previous
//
#include <hip/hip_runtime.h>

// xDeepFM CIN fused 3-layer kernel, MI355X (gfx950).
// Algebraic split: h-GEMM (rows 0..63) at full EMB + o-part as GEMV vs
// p[c=j*32+z] = sum_k h[j,k] inp[z,k].  f16 MFMA 32x32x16, fp32 accumulate.
// KEY (R4 post-mortem): per-CU TCP processes ~1 cache line/cycle; 64-lane
// gathers of W were the wall.  W is pre-shuffled into MFMA-fragment order so
// every A-fragment load is ONE coalesced 1KB dwordx4 (16 lines).
// Block = 4 batches, 4 waves; h-GEMM wave = (row-half, batch-pair) so one
// W-frag pair feeds 8 MFMAs.  pS/rS alias (LDS 73.3 KB -> 2 blocks/CU).

typedef _Float16 f16;
typedef _Float16 f16x4 __attribute__((ext_vector_type(4)));
typedef _Float16 f16x8 __attribute__((ext_vector_type(8)));
typedef float f32x4 __attribute__((ext_vector_type(4)));
typedef float f32x16 __attribute__((ext_vector_type(16)));

#define HSTR 72      // LDS row stride (f16) for inp/h: 144 B
#define PSTR 2064    // pS per-batch stride (f16): breaks 4-way bank aliasing

__device__ __forceinline__ f32x16 zero16() {
    f32x16 v;
#pragma unroll
    for (int i = 0; i < 16; ++i) v[i] = 0.0f;
    return v;
}

// ---------------- prep: W (fp32 row-major) -> f16 fragment-ordered ----------
// Fragment (mc, kk) of a region = 512 f16: element lane*8+i =
//   W[rbase + mc*32 + (lane&31)][kk*16 + (lane>>5)*8 + i]
// Regions (f16 offsets in ws):
//   H0 @      0: W0 rows  0..63, KK= 64  (65536)
//   O0 @  65536: W0 rows 64..127,KK= 64  (65536)
//   H1 @ 131072: W1 rows  0..63, KK=128  (131072)
//   O1 @ 262144: W1 rows 64..127,KK=128  (131072)
//   O2 @ 393216: W2 rows  0..127,KK=128  (262144)   total 655360 f16
__global__ void __launch_bounds__(256)
prep_frag(const float* __restrict__ W0, const float* __restrict__ W1,
          const float* __restrict__ W2, f16* __restrict__ dst)
{
    int g = (blockIdx.x * 256 + threadIdx.x) * 8;    // grid = 320
    const float* src; int base, KK, rbase;
    if (g < 65536)       { src = W0; base = 0;      KK = 64;  rbase = 0;  }
    else if (g < 131072) { src = W0; base = 65536;  KK = 64;  rbase = 64; }
    else if (g < 262144) { src = W1; base = 131072; KK = 128; rbase = 0;  }
    else if (g < 393216) { src = W1; base = 262144; KK = 128; rbase = 64; }
    else                 { src = W2; base = 393216; KK = 128; rbase = 0;  }
    int local = g - base;
    int frag  = local >> 9;
    int lane  = (local >> 3) & 63;
    int kk    = frag % KK;
    int mc    = frag / KK;
    int row   = rbase + mc * 32 + (lane & 31);
    int col   = kk * 16 + (lane >> 5) * 8;
    int IC    = KK * 16;
    const float* s = src + (size_t)row * IC + col;
    f16x8 o;
#pragma unroll
    for (int i = 0; i < 8; ++i) o[i] = (f16)s[i];
    *(f16x8*)(dst + g) = o;
}

// ---------------- p-GEMM: p[j,z] = sum_k h[j,k] inp[z,k] (M=HJ,N=32,K=64) ---
template <int HJ>
__device__ __forceinline__ void p_gemm(const f16* __restrict__ hsrc,
                                       const f16* __restrict__ inpb,
                                       f16* __restrict__ pSw, int t, int q)
{
    constexpr int MT = HJ / 32;
    f32x16 acc[MT];
#pragma unroll
    for (int m = 0; m < MT; ++m) acc[m] = zero16();
#pragma unroll
    for (int s = 0; s < 4; ++s) {
        int kc = s * 16 + q * 8;
        f16x8 b = *(const f16x8*)(inpb + t * HSTR + kc);          // inp[z=t][k]
#pragma unroll
        for (int m = 0; m < MT; ++m) {
            f16x8 a = *(const f16x8*)(hsrc + (m * 32 + t) * HSTR + kc);
            acc[m] = __builtin_amdgcn_mfma_f32_32x32x16_f16(a, b, acc[m], 0, 0, 0);
        }
    }
#pragma unroll
    for (int m = 0; m < MT; ++m)
#pragma unroll
        for (int r = 0; r < 16; ++r) {
            int j = m * 32 + (r & 3) + 8 * (r >> 2) + 4 * q;
            pSw[j * 32 + t] = (f16)acc[m][r];
        }
}

// ---------------- h-GEMM: rows [mc*32,+32) x 64 cols, 2 batches ------------
// Hfrag pre-offset by mc; per j: 2 coalesced frag loads feed 8 MFMAs.
template <int HJ>
__device__ __forceinline__ void h_gemm(const f16* __restrict__ Hfrag,
                                       const f16* __restrict__ h0,
                                       const f16* __restrict__ h1,
                                       int lane8, int t,
                                       const f16x8 (&ip)[2][2][2],
                                       f32x16 (&acc)[2][2])
{
#pragma unroll
    for (int b = 0; b < 2; ++b)
#pragma unroll
        for (int nh = 0; nh < 2; ++nh) acc[b][nh] = zero16();

    const f16* Wp = Hfrag + lane8;
    f16x8 wf0 = *(const f16x8*)(Wp);
    f16x8 wf1 = *(const f16x8*)(Wp + 512);
#pragma unroll 4
    for (int j = 0; j < HJ; ++j) {
        f16x8 cw0 = wf0, cw1 = wf1;
        int jn = j + 1 < HJ ? j + 1 : HJ - 1;     // clamped depth-1 prefetch
        wf0 = *(const f16x8*)(Wp + jn * 1024);
        wf1 = *(const f16x8*)(Wp + jn * 1024 + 512);
        f16 s00 = h0[j * HSTR + t],      s01 = h0[j * HSTR + 32 + t];
        f16 s10 = h1[j * HSTR + t],      s11 = h1[j * HSTR + 32 + t];
        acc[0][0] = __builtin_amdgcn_mfma_f32_32x32x16_f16(cw0, ip[0][0][0] * s00, acc[0][0], 0, 0, 0);
        acc[0][0] = __builtin_amdgcn_mfma_f32_32x32x16_f16(cw1, ip[0][1][0] * s00, acc[0][0], 0, 0, 0);
        acc[0][1] = __builtin_amdgcn_mfma_f32_32x32x16_f16(cw0, ip[0][0][1] * s01, acc[0][1], 0, 0, 0);
        acc[0][1] = __builtin_amdgcn_mfma_f32_32x32x16_f16(cw1, ip[0][1][1] * s01, acc[0][1], 0, 0, 0);
        acc[1][0] = __builtin_amdgcn_mfma_f32_32x32x16_f16(cw0, ip[1][0][0] * s10, acc[1][0], 0, 0, 0);
        acc[1][0] = __builtin_amdgcn_mfma_f32_32x32x16_f16(cw1, ip[1][1][0] * s10, acc[1][0], 0, 0, 0);
        acc[1][1] = __builtin_amdgcn_mfma_f32_32x32x16_f16(cw0, ip[1][0][1] * s11, acc[1][1], 0, 0, 0);
        acc[1][1] = __builtin_amdgcn_mfma_f32_32x32x16_f16(cw1, ip[1][1][1] * s11, acc[1][1], 0, 0, 0);
    }
}

// Write h_{l+1} rows [mc*32,+32) + bias into plain LDS (stride HSTR).
__device__ __forceinline__ void epi_h(const f32x16 (&acc)[2][2],
                                      f16* __restrict__ hb0, f16* __restrict__ hb1,
                                      const float* __restrict__ bl,
                                      int mc, int t, int q)
{
#pragma unroll
    for (int r = 0; r < 16; ++r) {
        int row = mc * 32 + (r & 3) + 8 * (r >> 2) + 4 * q;
        float bv = bl[row];
        hb0[row * HSTR + t]      = (f16)(acc[0][0][r] + bv);
        hb0[row * HSTR + 32 + t] = (f16)(acc[0][1][r] + bv);
        hb1[row * HSTR + t]      = (f16)(acc[1][0][r] + bv);
        hb1[row * HSTR + 32 + t] = (f16)(acc[1][1][r] + bv);
    }
}

// ---------------- o-GEMV: D[o, b<4] = sum_c Wo[o,c] p_b[c], K split 4 ways --
template <int ICN, int MCo>
__device__ __forceinline__ void o_gemv(const f16* __restrict__ Ofrag,
                                       const f16* __restrict__ pS,
                                       int w, int lane8, int t, int q,
                                       f32x16 (&acc)[MCo])
{
    constexpr int KK  = ICN / 16;
    constexpr int NKW = KK / 4;
    const int kk0 = w * NKW;
#pragma unroll
    for (int m = 0; m < MCo; ++m) acc[m] = zero16();
    const f16* pb = pS + (t & 3) * PSTR;
    const bool valid = t < 4;
    f16x8 zf;
#pragma unroll
    for (int i = 0; i < 8; ++i) zf[i] = (f16)0.0f;

    f16x8 wfr[MCo];
#pragma unroll
    for (int m = 0; m < MCo; ++m)
        wfr[m] = *(const f16x8*)(Ofrag + (m * KK + kk0) * 512 + lane8);
#pragma unroll 4
    for (int s = 0; s < NKW; ++s) {
        int kk = kk0 + s;
        f16x8 b = *(const f16x8*)(pb + kk * 16 + q * 8);
        b = valid ? b : zf;
        f16x8 cur[MCo];
#pragma unroll
        for (int m = 0; m < MCo; ++m) cur[m] = wfr[m];
        int sn = s + 1 < NKW ? s + 1 : NKW - 1;
#pragma unroll
        for (int m = 0; m < MCo; ++m)
            wfr[m] = *(const f16x8*)(Ofrag + (m * KK + kk0 + sn) * 512 + lane8);
#pragma unroll
        for (int m = 0; m < MCo; ++m)
            acc[m] = __builtin_amdgcn_mfma_f32_32x32x16_f16(cur[m], b, acc[m], 0, 0, 0);
    }
}

template <int MCo>
__device__ __forceinline__ void write_partials(const f32x16 (&acc)[MCo],
                                               float* __restrict__ rS,
                                               int w, int t, int q)
{
    if (t < 4) {
#pragma unroll
        for (int m = 0; m < MCo; ++m)
#pragma unroll
            for (int r = 0; r < 16; ++r) {
                int o = m * 32 + (r & 3) + 8 * (r >> 2) + 4 * q;
                rS[o * 16 + w * 4 + t] = acc[m][r];
            }
    }
}

__device__ __forceinline__ void reduce_out(const float* __restrict__ rS,
                                           float* __restrict__ out, int b0i,
                                           int colbase, const float* __restrict__ biasv,
                                           int nOut, int tid)
{
    int b = tid & 3;
    for (int o = tid >> 2; o < nOut; o += 64) {
        float s = rS[o * 16 + b] + rS[o * 16 + 4 + b] +
                  rS[o * 16 + 8 + b] + rS[o * 16 + 12 + b];
        out[(size_t)(b0i + b) * 256 + colbase + o] = s + 64.0f * biasv[o];
    }
}

__global__ void __launch_bounds__(256, 2)
cin_fused(const float* __restrict__ inp, const f16* __restrict__ Wf,
          const float* __restrict__ b0v, const float* __restrict__ b1v,
          const float* __restrict__ b2v, float* __restrict__ out)
{
    // LDS (73344 B): inpL [4][32*HSTR] @0 (18432) | hL [4][64*HSTR] @18432
    // (36864) | pS[4][PSTR] f16 / rS f32[128][16] union @55296 (16512) |
    // biasS[384] @71808 (1536).
    __shared__ __attribute__((aligned(16))) char smem[73344];
    f16*   inpL  = (f16*)smem;
    f16*   hL    = (f16*)(smem + 18432);
    f16*   pS    = (f16*)(smem + 55296);
    float* rS    = (float*)(smem + 55296);
    float* biasS = (float*)(smem + 71808);

    const int tid  = threadIdx.x;
    const int w    = tid >> 6;
    const int lane = tid & 63;
    const int t    = lane & 31;
    const int q    = lane >> 5;
    const int lane8 = lane * 8;
    const int mc   = w & 1;
    const int bp0  = (w >> 1) * 2;           // this wave's h-batch pair
    const int b0i  = blockIdx.x * 4;

    // Stage: wave w loads batch w (coalesced f32x4), writes inpL stride HSTR.
    {
        const float* ib = inp + (size_t)(b0i + w) * 2048;
        f16* dst = inpL + w * 32 * HSTR;
#pragma unroll
        for (int it = 0; it < 8; ++it) {
            int idx = it * 256 + lane * 4;
            f32x4 v = *(const f32x4*)(ib + idx);
            int z = idx >> 6, k = idx & 63;
            f16x4 h4;
            h4[0] = (f16)v[0]; h4[1] = (f16)v[1]; h4[2] = (f16)v[2]; h4[3] = (f16)v[3];
            *(f16x4*)(dst + z * HSTR + k) = h4;
        }
    }
    for (int idx = tid; idx < 384; idx += 256) {
        float v = (idx < 128) ? b0v[idx] : (idx < 256 ? b1v[idx - 128] : b2v[idx - 256]);
        biasS[idx] = v;
    }
    __syncthreads();                                   // B0

    // ip[b2][kq][nh][i] = inp[bp0+b2][z=kq*16+q*8+i][nh*32+t]
    f16x8 ip[2][2][2];
#pragma unroll
    for (int b2 = 0; b2 < 2; ++b2) {
        const f16* src = inpL + (bp0 + b2) * 32 * HSTR;
#pragma unroll
        for (int kq = 0; kq < 2; ++kq)
#pragma unroll
            for (int nh = 0; nh < 2; ++nh) {
                f16x8 v;
#pragma unroll
                for (int i = 0; i < 8; ++i)
                    v[i] = src[(kq * 16 + q * 8 + i) * HSTR + nh * 32 + t];
                ip[b2][kq][nh] = v;
            }
    }

    const f16* H0 = Wf;                 const f16* O0 = Wf + 65536;
    const f16* H1 = Wf + 131072;        const f16* O1 = Wf + 262144;
    const f16* O2 = Wf + 393216;
    const f16* myInp = inpL + w * 32 * HSTR;
    const f16* hp0 = inpL + bp0 * 32 * HSTR;
    const f16* hp1 = inpL + (bp0 + 1) * 32 * HSTR;
    f16* hb0 = hL + bp0 * 64 * HSTR;
    f16* hb1 = hL + (bp0 + 1) * 64 * HSTR;
    f32x16 hacc[2][2];

    // ================= Layer 0 (HJ=32, IC=1024) =================
    p_gemm<32>(myInp, myInp, pS + w * PSTR, t, q);
    __syncthreads();                                   // B1: pS ready
    {
        f32x16 oacc[2];
        o_gemv<1024, 2>(O0, pS, w, lane8, t, q, oacc);
        __syncthreads();                               // B2: pS reads done
        write_partials<2>(oacc, rS, w, t, q);
    }
    h_gemm<32>(H0 + mc * 64 * 512, hp0, hp1, lane8, t, ip, hacc);
    epi_h(hacc, hb0, hb1, biasS, mc, t, q);
    __syncthreads();                                   // B3: rS + hL ready
    reduce_out(rS, out, b0i, 0, biasS + 64, 64, tid);
    __syncthreads();                                   // B4: rS reads done

    // ================= Layer 1 (HJ=64, IC=2048) =================
    p_gemm<64>(hL + w * 64 * HSTR, myInp, pS + w * PSTR, t, q);
    __syncthreads();                                   // B5: pS ready
    {
        f32x16 oacc[2];
        o_gemv<2048, 2>(O1, pS, w, lane8, t, q, oacc);
        __syncthreads();                               // B6: pS reads done
        write_partials<2>(oacc, rS, w, t, q);
    }
    h_gemm<64>(H1 + mc * 128 * 512, hL + bp0 * 64 * HSTR, hL + (bp0 + 1) * 64 * HSTR,
               lane8, t, ip, hacc);
    __syncthreads();                                   // B7: all hL reads done, rS ready
    epi_h(hacc, hb0, hb1, biasS + 128, mc, t, q);
    reduce_out(rS, out, b0i, 64, biasS + 128 + 64, 64, tid);
    __syncthreads();                                   // B8: hL(new) ready, rS free

    // ================= Layer 2 (HJ=64, IC=2048, all 128 rows) ===
    p_gemm<64>(hL + w * 64 * HSTR, myInp, pS + w * PSTR, t, q);
    __syncthreads();                                   // B9: pS ready
    {
        f32x16 oacc[4];
        o_gemv<2048, 4>(O2, pS, w, lane8, t, q, oacc);
        __syncthreads();                               // B10: pS reads done
        write_partials<4>(oacc, rS, w, t, q);
    }
    __syncthreads();                                   // B11: rS ready
    reduce_out(rS, out, b0i, 128, biasS + 256, 128, tid);
}

extern "C" void kernel_launch(void* const* d_in, const int* in_sizes, int n_in,
                              void* d_out, int out_size, void* d_ws, size_t ws_size,
                              hipStream_t stream)
{
    const float* inp = (const float*)d_in[0];
    const float* W0  = (const float*)d_in[1];
    const float* b0  = (const float*)d_in[2];
    const float* W1  = (const float*)d_in[3];
    const float* b1  = (const float*)d_in[4];
    const float* W2  = (const float*)d_in[5];
    const float* b2  = (const float*)d_in[6];
    float* out = (float*)d_out;

    f16* Wf = (f16*)d_ws;             // 655360 f16 = 1.25 MB fragment-ordered
    prep_frag<<<320, 256, 0, stream>>>(W0, W1, W2, Wf);
    cin_fused<<<512, 256, 0, stream>>>(inp, Wf, b0, b1, b2, out);
}

// Round 6
// 167.529 us; speedup vs baseline: 1.8039x; 1.0127x over previous
//
#include <hip/hip_runtime.h>

// xDeepFM CIN fused 3-layer kernel, MI355X (gfx950).
// Algebraic split: h-GEMM (rows 0..63, full EMB) + o-part as MFMA GEMV vs
// p[c=j*32+z] = sum_k h[j,k] inp[z,k].  f16 MFMA 32x32x16, fp32 accumulate.
// W pre-shuffled to MFMA-fragment order (1KB coalesced dwordx4 per A-frag).
// R6: 2 batches/block, grid 1024, LDS 39.9KB -> 4 blocks/CU (16 waves/CU) so
// barrier drains + latency windows of one block hide under the other three.
// Barriers cut 12 -> 8 (separate rS, bias in regs/global).

typedef _Float16 f16;
typedef _Float16 f16x4 __attribute__((ext_vector_type(4)));
typedef _Float16 f16x8 __attribute__((ext_vector_type(8)));
typedef float f32x4 __attribute__((ext_vector_type(4)));
typedef float f32x16 __attribute__((ext_vector_type(16)));

#define HSTR 72      // inp/h LDS row stride (f16): 144B = 9*16B, b128-aligned
#define PSTR 2056    // pS per-batch stride (f16): 4112B, 16B-aligned, bank-skewed

__device__ __forceinline__ f32x16 zero16() {
    f32x16 v;
#pragma unroll
    for (int i = 0; i < 16; ++i) v[i] = 0.0f;
    return v;
}

// ---------------- prep: W (fp32 row-major) -> f16 fragment-ordered ----------
// Fragment (mc, kk) = 512 f16; element lane*8+i =
//   W[rbase + mc*32 + (lane&31)][kk*16 + (lane>>5)*8 + i]
// Regions (f16 offsets): H0@0 (W0 r0..63, KK=64) | O0@65536 (W0 r64..127) |
// H1@131072 (W1 r0..63, KK=128) | O1@262144 (W1 r64..127) | O2@393216 (W2 all).
__global__ void __launch_bounds__(256)
prep_frag(const float* __restrict__ W0, const float* __restrict__ W1,
          const float* __restrict__ W2, f16* __restrict__ dst)
{
    int g = (blockIdx.x * 256 + threadIdx.x) * 8;    // grid = 320
    const float* src; int base, KK, rbase;
    if (g < 65536)       { src = W0; base = 0;      KK = 64;  rbase = 0;  }
    else if (g < 131072) { src = W0; base = 65536;  KK = 64;  rbase = 64; }
    else if (g < 262144) { src = W1; base = 131072; KK = 128; rbase = 0;  }
    else if (g < 393216) { src = W1; base = 262144; KK = 128; rbase = 64; }
    else                 { src = W2; base = 393216; KK = 128; rbase = 0;  }
    int local = g - base;
    int frag  = local >> 9;
    int lane  = (local >> 3) & 63;
    int kk    = frag % KK;
    int mc    = frag / KK;
    int row   = rbase + mc * 32 + (lane & 31);
    int col   = kk * 16 + (lane >> 5) * 8;
    int IC    = KK * 16;
    const float* s = src + (size_t)row * IC + col;
    f16x8 o;
#pragma unroll
    for (int i = 0; i < 8; ++i) o[i] = (f16)s[i];
    *(f16x8*)(dst + g) = o;
}

// ---- p-chunk: p rows [jbase, jbase+32) for one batch (M=32,N=32,K=64) ------
__device__ __forceinline__ void p_chunk(const f16* __restrict__ hrows,
                                        const f16* __restrict__ inpb,
                                        f16* __restrict__ pSb, int jbase,
                                        int t, int q)
{
    f32x16 acc = zero16();
#pragma unroll
    for (int s = 0; s < 4; ++s) {
        int kc = s * 16 + q * 8;
        f16x8 b = *(const f16x8*)(inpb + t * HSTR + kc);   // inp[z=t][k]
        f16x8 a = *(const f16x8*)(hrows + t * HSTR + kc);  // h[jbase+t][k]
        acc = __builtin_amdgcn_mfma_f32_32x32x16_f16(a, b, acc, 0, 0, 0);
    }
#pragma unroll
    for (int r = 0; r < 16; ++r) {
        int j = jbase + (r & 3) + 8 * (r >> 2) + 4 * q;
        pSb[j * 32 + t] = (f16)acc[r];
    }
}

// ---- h-GEMM: rows [g*32,+32) x 64 cols, ONE batch; 2 W loads -> 4 MFMA/j ---
template <int HJ>
__device__ __forceinline__ void h_gemm1(const f16* __restrict__ Hfrag,
                                        const f16* __restrict__ hsrc,
                                        int lane8, int t,
                                        const f16x8 (&ip)[2][2],
                                        f32x16 (&acc)[2])
{
    acc[0] = zero16(); acc[1] = zero16();
    const f16* Wp = Hfrag + lane8;
    f16x8 wf0 = *(const f16x8*)(Wp);
    f16x8 wf1 = *(const f16x8*)(Wp + 512);
#pragma unroll 4
    for (int j = 0; j < HJ; ++j) {
        f16x8 cw0 = wf0, cw1 = wf1;
        int jn = j + 1 < HJ ? j + 1 : HJ - 1;     // clamped depth-1 prefetch
        wf0 = *(const f16x8*)(Wp + jn * 1024);
        wf1 = *(const f16x8*)(Wp + jn * 1024 + 512);
        f16 s0 = hsrc[j * HSTR + t];              // h[j][t]
        f16 s1 = hsrc[j * HSTR + 32 + t];         // h[j][32+t]
        acc[0] = __builtin_amdgcn_mfma_f32_32x32x16_f16(cw0, ip[0][0] * s0, acc[0], 0, 0, 0);
        acc[1] = __builtin_amdgcn_mfma_f32_32x32x16_f16(cw0, ip[0][1] * s1, acc[1], 0, 0, 0);
        acc[0] = __builtin_amdgcn_mfma_f32_32x32x16_f16(cw1, ip[1][0] * s0, acc[0], 0, 0, 0);
        acc[1] = __builtin_amdgcn_mfma_f32_32x32x16_f16(cw1, ip[1][1] * s1, acc[1], 0, 0, 0);
    }
}

// Write h_{l+1} rows [g*32,+32) + bias (prefetched regs) for one batch.
__device__ __forceinline__ void epi_h1(const f32x16 (&acc)[2], f16* __restrict__ hdst,
                                       const float (&bve)[16], int g, int t, int q)
{
#pragma unroll
    for (int r = 0; r < 16; ++r) {
        int row = g * 32 + (r & 3) + 8 * (r >> 2) + 4 * q;
        hdst[row * HSTR + t]      = (f16)(acc[0][r] + bve[r]);
        hdst[row * HSTR + 32 + t] = (f16)(acc[1][r] + bve[r]);
    }
}

// ---- o-GEMV: D[o, b<2] = sum_c Wo[o,c] p_b[c]; K split across 4 waves ------
template <int ICN, int MCo>
__device__ __forceinline__ void o_gemv(const f16* __restrict__ Ofrag,
                                       const f16* __restrict__ pS,
                                       int w, int lane8, int t, int q,
                                       f32x16 (&acc)[MCo])
{
    constexpr int KK  = ICN / 16;
    constexpr int NKW = KK / 4;
    const int kk0 = w * NKW;
#pragma unroll
    for (int m = 0; m < MCo; ++m) acc[m] = zero16();
    const f16* pb = pS + (t & 1) * PSTR;
    const bool valid = t < 2;
    f16x8 zf;
#pragma unroll
    for (int i = 0; i < 8; ++i) zf[i] = (f16)0.0f;

    f16x8 wfr[MCo];
#pragma unroll
    for (int m = 0; m < MCo; ++m)
        wfr[m] = *(const f16x8*)(Ofrag + (m * KK + kk0) * 512 + lane8);
#pragma unroll 4
    for (int s = 0; s < NKW; ++s) {
        int kk = kk0 + s;
        f16x8 b = *(const f16x8*)(pb + kk * 16 + q * 8);
        b = valid ? b : zf;
        f16x8 cur[MCo];
#pragma unroll
        for (int m = 0; m < MCo; ++m) cur[m] = wfr[m];
        int sn = s + 1 < NKW ? s + 1 : NKW - 1;
#pragma unroll
        for (int m = 0; m < MCo; ++m)
            wfr[m] = *(const f16x8*)(Ofrag + (m * KK + kk0 + sn) * 512 + lane8);
#pragma unroll
        for (int m = 0; m < MCo; ++m)
            acc[m] = __builtin_amdgcn_mfma_f32_32x32x16_f16(cur[m], b, acc[m], 0, 0, 0);
    }
}

template <int MCo>
__device__ __forceinline__ void write_partials(const f32x16 (&acc)[MCo],
                                               float* __restrict__ rS,
                                               int w, int t, int q)
{
    if (t < 2) {
#pragma unroll
        for (int m = 0; m < MCo; ++m)
#pragma unroll
            for (int r = 0; r < 16; ++r) {
                int o = m * 32 + (r & 3) + 8 * (r >> 2) + 4 * q;
                rS[o * 8 + w * 2 + t] = acc[m][r];
            }
    }
}

__device__ __forceinline__ void reduce_out(const float* __restrict__ rS,
                                           float* __restrict__ out, int b0i,
                                           int colbase, const float* __restrict__ biasv,
                                           int nOut, int tid)
{
    int b = tid & 1;
    for (int o = tid >> 1; o < nOut; o += 128) {
        float s = rS[o * 8 + b] + rS[o * 8 + 2 + b] +
                  rS[o * 8 + 4 + b] + rS[o * 8 + 6 + b];
        out[(size_t)(b0i + b) * 256 + colbase + o] = s + 64.0f * biasv[o];
    }
}

__device__ __forceinline__ void load_bias(const float* __restrict__ bl,
                                          float (&bve)[16], int g, int q)
{
#pragma unroll
    for (int r = 0; r < 16; ++r)
        bve[r] = bl[g * 32 + (r & 3) + 8 * (r >> 2) + 4 * q];
}

__global__ void __launch_bounds__(256, 4)
cin_fused(const float* __restrict__ inp, const f16* __restrict__ Wf,
          const float* __restrict__ b0v, const float* __restrict__ b1v,
          const float* __restrict__ b2v, float* __restrict__ out)
{
    // LDS (39968 B): inpL [2][32*HSTR] @0 (9216) | hL [2][64*HSTR] @9216
    // (18432) | pS [2][PSTR] f16 @27648 (8224) | rS f32 [128][8] @35872 (4096)
    __shared__ __attribute__((aligned(16))) char smem[39968];
    f16*   inpL = (f16*)smem;
    f16*   hL   = (f16*)(smem + 9216);
    f16*   pS   = (f16*)(smem + 27648);
    float* rS   = (float*)(smem + 35872);

    const int tid   = threadIdx.x;
    const int w     = tid >> 6;
    const int lane  = tid & 63;
    const int t     = lane & 31;
    const int q     = lane >> 5;
    const int lane8 = lane * 8;
    const int b     = w & 1;         // this wave's batch
    const int g     = w >> 1;        // row-half / stage-half role
    const int b0i   = blockIdx.x * 2;

    const f16* myInp = inpL + b * 32 * HSTR;
    f16* myH         = hL + b * 64 * HSTR;
    f16* pSb         = pS + b * PSTR;

    // Stage: wave (b,g) loads half g of batch b (coalesced f32x4 -> f16x4).
    {
        const float* ib = inp + (size_t)(b0i + b) * 2048;
        f16* dst = inpL + b * 32 * HSTR;
#pragma unroll
        for (int it = 0; it < 4; ++it) {
            int idx = (g * 4 + it) * 256 + lane * 4;
            f32x4 v = *(const f32x4*)(ib + idx);
            int z = idx >> 6, k = idx & 63;
            f16x4 h4;
            h4[0] = (f16)v[0]; h4[1] = (f16)v[1]; h4[2] = (f16)v[2]; h4[3] = (f16)v[3];
            *(f16x4*)(dst + z * HSTR + k) = h4;
        }
    }
    __syncthreads();                                   // B0: inpL ready

    // ip[kq][nh][i] = inp[b][z=kq*16+q*8+i][nh*32+t]
    f16x8 ip[2][2];
#pragma unroll
    for (int kq = 0; kq < 2; ++kq)
#pragma unroll
        for (int nh = 0; nh < 2; ++nh) {
            f16x8 v;
#pragma unroll
            for (int i = 0; i < 8; ++i)
                v[i] = myInp[(kq * 16 + q * 8 + i) * HSTR + nh * 32 + t];
            ip[kq][nh] = v;
        }

    const f16* H0 = Wf;                 const f16* O0 = Wf + 65536;
    const f16* H1 = Wf + 131072;        const f16* O1 = Wf + 262144;
    const f16* O2 = Wf + 393216;
    f32x16 hacc[2];
    float bve[16];

    // ================= Layer 0 (HJ=32, IC=1024) =================
    if (g == 0) p_chunk(myInp, myInp, pSb, 0, t, q);
    __syncthreads();                                   // B1: pS ready
    {
        f32x16 oacc[2];
        o_gemv<1024, 2>(O0, pS, w, lane8, t, q, oacc);
        write_partials<2>(oacc, rS, w, t, q);
    }
    load_bias(b0v, bve, g, q);
    h_gemm1<32>(H0 + g * 64 * 512, myInp, lane8, t, ip, hacc);
    epi_h1(hacc, myH, bve, g, t, q);
    __syncthreads();                                   // B2: rS + hL(h1) ready
    reduce_out(rS, out, b0i, 0, b0v + 64, 64, tid);
    p_chunk(myH + g * 32 * HSTR, myInp, pSb, g * 32, t, q);
    __syncthreads();                                   // B3: pS ready (rS reads done)

    // ================= Layer 1 (HJ=64, IC=2048) =================
    {
        f32x16 oacc[2];
        o_gemv<2048, 2>(O1, pS, w, lane8, t, q, oacc);
        write_partials<2>(oacc, rS, w, t, q);
    }
    load_bias(b1v, bve, g, q);
    h_gemm1<64>(H1 + g * 128 * 512, myH, lane8, t, ip, hacc);
    __syncthreads();                                   // B4: all h1 reads done, rS ready
    epi_h1(hacc, myH, bve, g, t, q);                   // overwrite h1 -> h2
    reduce_out(rS, out, b0i, 64, b1v + 64, 64, tid);
    __syncthreads();                                   // B5: hL(h2) ready, rS reads done
    p_chunk(myH + g * 32 * HSTR, myInp, pSb, g * 32, t, q);
    __syncthreads();                                   // B6: pS ready

    // ================= Layer 2 (all 128 rows -> out cols 128..255) =====
    {
        f32x16 oacc[4];
        o_gemv<2048, 4>(O2, pS, w, lane8, t, q, oacc);
        write_partials<4>(oacc, rS, w, t, q);
    }
    __syncthreads();                                   // B7: rS ready
    reduce_out(rS, out, b0i, 128, b2v, 128, tid);
}

extern "C" void kernel_launch(void* const* d_in, const int* in_sizes, int n_in,
                              void* d_out, int out_size, void* d_ws, size_t ws_size,
                              hipStream_t stream)
{
    const float* inp = (const float*)d_in[0];
    const float* W0  = (const float*)d_in[1];
    const float* b0  = (const float*)d_in[2];
    const float* W1  = (const float*)d_in[3];
    const float* b1  = (const float*)d_in[4];
    const float* W2  = (const float*)d_in[5];
    const float* b2  = (const float*)d_in[6];
    float* out = (float*)d_out;

    f16* Wf = (f16*)d_ws;             // 655360 f16 = 1.25 MB fragment-ordered
    prep_frag<<<320, 256, 0, stream>>>(W0, W1, W2, Wf);
    cin_fused<<<1024, 256, 0, stream>>>(inp, Wf, b0, b1, b2, out);
}

// Round 7
// 156.616 us; speedup vs baseline: 1.9296x; 1.0697x over previous
//
#include <hip/hip_runtime.h>

// xDeepFM CIN fused 3-layer kernel, MI355X (gfx950).
// Algebraic split: h-GEMM (rows 0..63, full EMB) + o-part as MFMA GEMV vs
// p[c=j*32+z] = sum_k h[j,k] inp[z,k].  f16 MFMA 32x32x16, fp32 accumulate.
// W pre-shuffled to MFMA-fragment order (1KB coalesced dwordx4 per A-frag).
// R7: deep ping-pong register prefetch (distance 8-12 K-steps, vmcnt ~16 deep)
// in h_gemm and o_gemv — R6 showed the limiter is per-wave dependent-chain
// latency (depth-1 prefetch covered ~34 of ~200 cyc L2 latency), not occupancy.

typedef _Float16 f16;
typedef _Float16 f16x4 __attribute__((ext_vector_type(4)));
typedef _Float16 f16x8 __attribute__((ext_vector_type(8)));
typedef float f32x4 __attribute__((ext_vector_type(4)));
typedef float f32x16 __attribute__((ext_vector_type(16)));

#define HSTR 72      // inp/h LDS row stride (f16): 144B = 9*16B, b128-aligned
#define PSTR 2056    // pS per-batch stride (f16)

__device__ __forceinline__ f32x16 zero16() {
    f32x16 v;
#pragma unroll
    for (int i = 0; i < 16; ++i) v[i] = 0.0f;
    return v;
}
__device__ __forceinline__ f16x8 zero8h() {
    f16x8 v;
#pragma unroll
    for (int i = 0; i < 8; ++i) v[i] = (f16)0.0f;
    return v;
}

// ---------------- prep: W (fp32 row-major) -> f16 fragment-ordered ----------
// Fragment (mc, kk) = 512 f16; element lane*8+i =
//   W[rbase + mc*32 + (lane&31)][kk*16 + (lane>>5)*8 + i]
// Regions (f16 offsets): H0@0 (W0 r0..63, KK=64) | O0@65536 (W0 r64..127) |
// H1@131072 (W1 r0..63, KK=128) | O1@262144 (W1 r64..127) | O2@393216 (W2 all).
__global__ void __launch_bounds__(256)
prep_frag(const float* __restrict__ W0, const float* __restrict__ W1,
          const float* __restrict__ W2, f16* __restrict__ dst)
{
    int g = (blockIdx.x * 256 + threadIdx.x) * 8;    // grid = 320
    const float* src; int base, KK, rbase;
    if (g < 65536)       { src = W0; base = 0;      KK = 64;  rbase = 0;  }
    else if (g < 131072) { src = W0; base = 65536;  KK = 64;  rbase = 64; }
    else if (g < 262144) { src = W1; base = 131072; KK = 128; rbase = 0;  }
    else if (g < 393216) { src = W1; base = 262144; KK = 128; rbase = 64; }
    else                 { src = W2; base = 393216; KK = 128; rbase = 0;  }
    int local = g - base;
    int frag  = local >> 9;
    int lane  = (local >> 3) & 63;
    int kk    = frag % KK;
    int mc    = frag / KK;
    int row   = rbase + mc * 32 + (lane & 31);
    int col   = kk * 16 + (lane >> 5) * 8;
    int IC    = KK * 16;
    const float* s = src + (size_t)row * IC + col;
    f16x8 o;
#pragma unroll
    for (int i = 0; i < 8; ++i) o[i] = (f16)s[i];
    *(f16x8*)(dst + g) = o;
}

// ---- p-chunk: p rows [jbase, jbase+32) for one batch (M=32,N=32,K=64) ------
__device__ __forceinline__ void p_chunk(const f16* __restrict__ hrows,
                                        const f16* __restrict__ inpb,
                                        f16* __restrict__ pSb, int jbase,
                                        int t, int q)
{
    f32x16 acc = zero16();
#pragma unroll
    for (int s = 0; s < 4; ++s) {
        int kc = s * 16 + q * 8;
        f16x8 b = *(const f16x8*)(inpb + t * HSTR + kc);   // inp[z=t][k]
        f16x8 a = *(const f16x8*)(hrows + t * HSTR + kc);  // h[jbase+t][k]
        acc = __builtin_amdgcn_mfma_f32_32x32x16_f16(a, b, acc, 0, 0, 0);
    }
#pragma unroll
    for (int r = 0; r < 16; ++r) {
        int j = jbase + (r & 3) + 8 * (r >> 2) + 4 * q;
        pSb[j * 32 + t] = (f16)acc[r];
    }
}

// ---- h-GEMM: rows [g*32,+32) x 64 cols, one batch --------------------------
// Ping-pong groups of 4 j; W-frags + h-scalars prefetched 8-12 j ahead.
template <int HJ>
__device__ __forceinline__ void h_gemm1(const f16* __restrict__ Hfrag,
                                        const f16* __restrict__ hsrc,
                                        int lane8, int t,
                                        const f16x8 (&ip)[2][2],
                                        f32x16 (&acc)[2])
{
    acc[0] = zero16(); acc[1] = zero16();
    const f16* Wp = Hfrag + lane8;
    f16x8 wb[2][8];
    f16   sb[2][8];
#pragma unroll
    for (int r = 0; r < 4; ++r) {
        wb[0][2*r]   = *(const f16x8*)(Wp + r * 1024);
        wb[0][2*r+1] = *(const f16x8*)(Wp + r * 1024 + 512);
        wb[1][2*r]   = *(const f16x8*)(Wp + (4 + r) * 1024);
        wb[1][2*r+1] = *(const f16x8*)(Wp + (4 + r) * 1024 + 512);
        sb[0][2*r]   = hsrc[r * HSTR + t];
        sb[0][2*r+1] = hsrc[r * HSTR + 32 + t];
        sb[1][2*r]   = hsrc[(4 + r) * HSTR + t];
        sb[1][2*r+1] = hsrc[(4 + r) * HSTR + 32 + t];
    }
    for (int jj = 0; jj < HJ; jj += 8) {
        int jA = (jj + 8  <= HJ - 4) ? jj + 8  : HJ - 4;   // clamped refill idx
        int jB = (jj + 12 <= HJ - 4) ? jj + 12 : HJ - 4;
#pragma unroll
        for (int ph = 0; ph < 2; ++ph) {
            int jn = ph ? jB : jA;
            f16x8 c[8]; f16 s[8];
#pragma unroll
            for (int r = 0; r < 8; ++r) { c[r] = wb[ph][r]; s[r] = sb[ph][r]; }
#pragma unroll
            for (int r = 0; r < 4; ++r) {               // refill phase ph
                wb[ph][2*r]   = *(const f16x8*)(Wp + (jn + r) * 1024);
                wb[ph][2*r+1] = *(const f16x8*)(Wp + (jn + r) * 1024 + 512);
                sb[ph][2*r]   = hsrc[(jn + r) * HSTR + t];
                sb[ph][2*r+1] = hsrc[(jn + r) * HSTR + 32 + t];
            }
#pragma unroll
            for (int r = 0; r < 4; ++r) {               // consume group
                f16 s0 = s[2*r], s1 = s[2*r+1];
                acc[0] = __builtin_amdgcn_mfma_f32_32x32x16_f16(c[2*r],   ip[0][0] * s0, acc[0], 0, 0, 0);
                acc[1] = __builtin_amdgcn_mfma_f32_32x32x16_f16(c[2*r],   ip[0][1] * s1, acc[1], 0, 0, 0);
                acc[0] = __builtin_amdgcn_mfma_f32_32x32x16_f16(c[2*r+1], ip[1][0] * s0, acc[0], 0, 0, 0);
                acc[1] = __builtin_amdgcn_mfma_f32_32x32x16_f16(c[2*r+1], ip[1][1] * s1, acc[1], 0, 0, 0);
            }
        }
    }
}

// Write h_{l+1} rows [g*32,+32) + bias (prefetched regs) for one batch.
__device__ __forceinline__ void epi_h1(const f32x16 (&acc)[2], f16* __restrict__ hdst,
                                       const float (&bve)[16], int g, int t, int q)
{
#pragma unroll
    for (int r = 0; r < 16; ++r) {
        int row = g * 32 + (r & 3) + 8 * (r >> 2) + 4 * q;
        hdst[row * HSTR + t]      = (f16)(acc[0][r] + bve[r]);
        hdst[row * HSTR + 32 + t] = (f16)(acc[1][r] + bve[r]);
    }
}

// ---- o-GEMV: 64 O-rows (2 row-blocks), K split across 4 waves --------------
// Ping-pong groups of 4 k-steps, refill 8-12 steps ahead.
template <int ICN>
__device__ __forceinline__ void o_gemv2(const f16* __restrict__ Ofrag,
                                        const f16* __restrict__ pS,
                                        int w, int lane8, int t, int q,
                                        f32x16 (&acc)[2])
{
    constexpr int KK  = ICN / 16;
    constexpr int NKW = KK / 4;          // 16 or 32
    const int kk0 = w * NKW;
    acc[0] = zero16(); acc[1] = zero16();
    const f16* pb = pS + (t & 1) * PSTR;
    const bool valid = t < 2;
    const f16x8 zf = zero8h();
    const f16* W0p = Ofrag + kk0 * 512 + lane8;          // row-block 0
    const f16* W1p = Ofrag + (KK + kk0) * 512 + lane8;   // row-block 1
    f16x8 wb[2][8];
#pragma unroll
    for (int g = 0; g < 4; ++g) {
        wb[0][2*g]   = *(const f16x8*)(W0p + g * 512);
        wb[0][2*g+1] = *(const f16x8*)(W1p + g * 512);
        wb[1][2*g]   = *(const f16x8*)(W0p + (4 + g) * 512);
        wb[1][2*g+1] = *(const f16x8*)(W1p + (4 + g) * 512);
    }
    for (int s = 0; s < NKW; s += 8) {
        int sA = (s + 8  <= NKW - 4) ? s + 8  : NKW - 4;
        int sB = (s + 12 <= NKW - 4) ? s + 12 : NKW - 4;
#pragma unroll
        for (int ph = 0; ph < 2; ++ph) {
            int sn = ph ? sB : sA;
            int sc = s + ph * 4;
            f16x8 c[8];
#pragma unroll
            for (int g = 0; g < 8; ++g) c[g] = wb[ph][g];
#pragma unroll
            for (int g = 0; g < 4; ++g) {               // refill
                wb[ph][2*g]   = *(const f16x8*)(W0p + (sn + g) * 512);
                wb[ph][2*g+1] = *(const f16x8*)(W1p + (sn + g) * 512);
            }
#pragma unroll
            for (int g = 0; g < 4; ++g) {               // consume
                f16x8 b = *(const f16x8*)(pb + (kk0 + sc + g) * 16 + q * 8);
                b = valid ? b : zf;
                acc[0] = __builtin_amdgcn_mfma_f32_32x32x16_f16(c[2*g],   b, acc[0], 0, 0, 0);
                acc[1] = __builtin_amdgcn_mfma_f32_32x32x16_f16(c[2*g+1], b, acc[1], 0, 0, 0);
            }
        }
    }
}

__device__ __forceinline__ void write_partials(const f32x16 (&acc)[2],
                                               float* __restrict__ rS,
                                               int obase, int w, int t, int q)
{
    if (t < 2) {
#pragma unroll
        for (int m = 0; m < 2; ++m)
#pragma unroll
            for (int r = 0; r < 16; ++r) {
                int o = obase + m * 32 + (r & 3) + 8 * (r >> 2) + 4 * q;
                rS[o * 8 + w * 2 + t] = acc[m][r];
            }
    }
}

__device__ __forceinline__ void reduce_out(const float* __restrict__ rS,
                                           float* __restrict__ out, int b0i,
                                           int colbase, const float* __restrict__ biasv,
                                           int nOut, int tid)
{
    int b = tid & 1;
    for (int o = tid >> 1; o < nOut; o += 128) {
        float s = rS[o * 8 + b] + rS[o * 8 + 2 + b] +
                  rS[o * 8 + 4 + b] + rS[o * 8 + 6 + b];
        out[(size_t)(b0i + b) * 256 + colbase + o] = s + 64.0f * biasv[o];
    }
}

__device__ __forceinline__ void load_bias(const float* __restrict__ bl,
                                          float (&bve)[16], int g, int q)
{
#pragma unroll
    for (int r = 0; r < 16; ++r)
        bve[r] = bl[g * 32 + (r & 3) + 8 * (r >> 2) + 4 * q];
}

__global__ void __launch_bounds__(256, 3)
cin_fused(const float* __restrict__ inp, const f16* __restrict__ Wf,
          const float* __restrict__ b0v, const float* __restrict__ b1v,
          const float* __restrict__ b2v, float* __restrict__ out)
{
    // LDS (39968 B): inpL [2][32*HSTR] @0 (9216) | hL [2][64*HSTR] @9216
    // (18432) | pS [2][PSTR] f16 @27648 (8224) | rS f32 [128][8] @35872 (4096)
    __shared__ __attribute__((aligned(16))) char smem[39968];
    f16*   inpL = (f16*)smem;
    f16*   hL   = (f16*)(smem + 9216);
    f16*   pS   = (f16*)(smem + 27648);
    float* rS   = (float*)(smem + 35872);

    const int tid   = threadIdx.x;
    const int w     = tid >> 6;
    const int lane  = tid & 63;
    const int t     = lane & 31;
    const int q     = lane >> 5;
    const int lane8 = lane * 8;
    const int b     = w & 1;         // this wave's batch
    const int g     = w >> 1;        // row-half / stage-half role
    const int b0i   = blockIdx.x * 2;

    const f16* myInp = inpL + b * 32 * HSTR;
    f16* myH         = hL + b * 64 * HSTR;
    f16* pSb         = pS + b * PSTR;

    // Stage: wave (b,g) loads half g of batch b (coalesced f32x4 -> f16x4).
    {
        const float* ib = inp + (size_t)(b0i + b) * 2048;
        f16* dst = inpL + b * 32 * HSTR;
#pragma unroll
        for (int it = 0; it < 4; ++it) {
            int idx = (g * 4 + it) * 256 + lane * 4;
            f32x4 v = *(const f32x4*)(ib + idx);
            int z = idx >> 6, k = idx & 63;
            f16x4 h4;
            h4[0] = (f16)v[0]; h4[1] = (f16)v[1]; h4[2] = (f16)v[2]; h4[3] = (f16)v[3];
            *(f16x4*)(dst + z * HSTR + k) = h4;
        }
    }
    __syncthreads();                                   // B0: inpL ready

    // ip[kq][nh][i] = inp[b][z=kq*16+q*8+i][nh*32+t]
    f16x8 ip[2][2];
#pragma unroll
    for (int kq = 0; kq < 2; ++kq)
#pragma unroll
        for (int nh = 0; nh < 2; ++nh) {
            f16x8 v;
#pragma unroll
            for (int i = 0; i < 8; ++i)
                v[i] = myInp[(kq * 16 + q * 8 + i) * HSTR + nh * 32 + t];
            ip[kq][nh] = v;
        }

    const f16* H0 = Wf;                 const f16* O0 = Wf + 65536;
    const f16* H1 = Wf + 131072;        const f16* O1 = Wf + 262144;
    const f16* O2 = Wf + 393216;
    f32x16 hacc[2];
    float bve[16];

    // ================= Layer 0 (HJ=32, IC=1024) =================
    if (g == 0) p_chunk(myInp, myInp, pSb, 0, t, q);
    __syncthreads();                                   // B1: pS ready
    {
        f32x16 oacc[2];
        o_gemv2<1024>(O0, pS, w, lane8, t, q, oacc);
        write_partials(oacc, rS, 0, w, t, q);
    }
    h_gemm1<32>(H0 + g * 64 * 512, myInp, lane8, t, ip, hacc);
    load_bias(b0v, bve, g, q);
    epi_h1(hacc, myH, bve, g, t, q);
    __syncthreads();                                   // B2: rS + hL(h1) ready
    reduce_out(rS, out, b0i, 0, b0v + 64, 64, tid);
    p_chunk(myH + g * 32 * HSTR, myInp, pSb, g * 32, t, q);
    __syncthreads();                                   // B3: pS ready (rS reads done)

    // ================= Layer 1 (HJ=64, IC=2048) =================
    {
        f32x16 oacc[2];
        o_gemv2<2048>(O1, pS, w, lane8, t, q, oacc);
        write_partials(oacc, rS, 0, w, t, q);
    }
    h_gemm1<64>(H1 + g * 128 * 512, myH, lane8, t, ip, hacc);
    load_bias(b1v, bve, g, q);
    __syncthreads();                                   // B4: all h1 reads done, rS ready
    epi_h1(hacc, myH, bve, g, t, q);                   // overwrite h1 -> h2
    reduce_out(rS, out, b0i, 64, b1v + 64, 64, tid);
    __syncthreads();                                   // B5: hL(h2) ready, rS reads done
    p_chunk(myH + g * 32 * HSTR, myInp, pSb, g * 32, t, q);
    __syncthreads();                                   // B6: pS ready

    // ================= Layer 2 (all 128 rows -> out cols 128..255) =====
    {
        f32x16 oacc[2];
        o_gemv2<2048>(O2, pS, w, lane8, t, q, oacc);
        write_partials(oacc, rS, 0, w, t, q);
        o_gemv2<2048>(O2 + 2 * 128 * 512, pS, w, lane8, t, q, oacc);
        write_partials(oacc, rS, 64, w, t, q);
    }
    __syncthreads();                                   // B7: rS ready
    reduce_out(rS, out, b0i, 128, b2v, 128, tid);
}

extern "C" void kernel_launch(void* const* d_in, const int* in_sizes, int n_in,
                              void* d_out, int out_size, void* d_ws, size_t ws_size,
                              hipStream_t stream)
{
    const float* inp = (const float*)d_in[0];
    const float* W0  = (const float*)d_in[1];
    const float* b0  = (const float*)d_in[2];
    const float* W1  = (const float*)d_in[3];
    const float* b1  = (const float*)d_in[4];
    const float* W2  = (const float*)d_in[5];
    const float* b2  = (const float*)d_in[6];
    float* out = (float*)d_out;

    f16* Wf = (f16*)d_ws;             // 655360 f16 = 1.25 MB fragment-ordered
    prep_frag<<<320, 256, 0, stream>>>(W0, W1, W2, Wf);
    cin_fused<<<1024, 256, 0, stream>>>(inp, Wf, b0, b1, b2, out);
}

// Round 8
// 148.101 us; speedup vs baseline: 2.0405x; 1.0575x over previous
//
#include <hip/hip_runtime.h>

// xDeepFM CIN, MI355X (gfx950) — two-kernel split.
// Kernel 1 (cin_h): per-batch h-chain (h-GEMMs rows 0..63) + p-vectors
//   p_l[c=j*32+z] = sum_k h_l[j,k] inp[z,k]  written f16 to workspace.
// Kernel 2 (cin_out): out columns as REAL GEMMs  D[o, batch] = W_o @ p,
//   N = 32-batch tiles -> full MFMA N-efficiency (R7's o-GEMV used 2/32 cols).
// W pre-shuffled to MFMA-fragment order (1KB coalesced dwordx4 per A-frag).

typedef _Float16 f16;
typedef _Float16 f16x4 __attribute__((ext_vector_type(4)));
typedef _Float16 f16x8 __attribute__((ext_vector_type(8)));
typedef float f32x4 __attribute__((ext_vector_type(4)));
typedef float f32x16 __attribute__((ext_vector_type(16)));

#define HSTR 72      // inp/h LDS row stride (f16): 144B, b128-aligned
#define PT   520     // kernel-2 P-tile LDS row stride (f16): 4-way bank alias max
#define CK   512     // kernel-2 K-chunk (c elements)
#define PBS  5120    // pW per-batch stride (f16): p0(1024)+p1(2048)+p2(2048)

__device__ __forceinline__ f32x16 zero16() {
    f32x16 v;
#pragma unroll
    for (int i = 0; i < 16; ++i) v[i] = 0.0f;
    return v;
}

// ---------------- prep: W (fp32 row-major) -> f16 fragment-ordered ----------
// Fragment (mc, kk) = 512 f16; element lane*8+i =
//   W[rbase + mc*32 + (lane&31)][kk*16 + (lane>>5)*8 + i]
// Regions (f16 offsets): H0@0 (W0 r0..63, KK=64) | O0@65536 (W0 r64..127) |
// H1@131072 (W1 r0..63, KK=128) | O1@262144 (W1 r64..127) | O2@393216 (W2 all).
__global__ void __launch_bounds__(256)
prep_frag(const float* __restrict__ W0, const float* __restrict__ W1,
          const float* __restrict__ W2, f16* __restrict__ dst)
{
    int g = (blockIdx.x * 256 + threadIdx.x) * 8;    // grid = 320
    const float* src; int base, KK, rbase;
    if (g < 65536)       { src = W0; base = 0;      KK = 64;  rbase = 0;  }
    else if (g < 131072) { src = W0; base = 65536;  KK = 64;  rbase = 64; }
    else if (g < 262144) { src = W1; base = 131072; KK = 128; rbase = 0;  }
    else if (g < 393216) { src = W1; base = 262144; KK = 128; rbase = 64; }
    else                 { src = W2; base = 393216; KK = 128; rbase = 0;  }
    int local = g - base;
    int frag  = local >> 9;
    int lane  = (local >> 3) & 63;
    int kk    = frag % KK;
    int mc    = frag / KK;
    int row   = rbase + mc * 32 + (lane & 31);
    int col   = kk * 16 + (lane >> 5) * 8;
    int IC    = KK * 16;
    const float* s = src + (size_t)row * IC + col;
    f16x8 o;
#pragma unroll
    for (int i = 0; i < 8; ++i) o[i] = (f16)s[i];
    *(f16x8*)(dst + g) = o;
}

// ---- p-chunk: p rows [jb, jb+32) of one batch -> GLOBAL (M=32,N=32,K=64) ---
__device__ __forceinline__ void p_chunk_g(const f16* __restrict__ hrows,
                                          const f16* __restrict__ inpb,
                                          f16* __restrict__ pdst,  // + b*PBS + poff + jb*32
                                          int t, int q)
{
    f32x16 acc = zero16();
#pragma unroll
    for (int s = 0; s < 4; ++s) {
        int kc = s * 16 + q * 8;
        f16x8 b = *(const f16x8*)(inpb + t * HSTR + kc);   // inp[z=t][k]
        f16x8 a = *(const f16x8*)(hrows + t * HSTR + kc);  // h[jb+t][k]
        acc = __builtin_amdgcn_mfma_f32_32x32x16_f16(a, b, acc, 0, 0, 0);
    }
#pragma unroll
    for (int r = 0; r < 16; ++r) {
        int row = (r & 3) + 8 * (r >> 2) + 4 * q;          // local j
        pdst[row * 32 + t] = (f16)acc[r];
    }
}

// ---- h-GEMM pair: rows [g*32,+32) x 64 cols, TWO batches ------------------
// Per j: 2 coalesced W-frag loads feed 8 MFMAs.  Ping-pong groups of 2 j,
// refill 4-6 j ahead (in-flight depth ~8 loads, fits VGPR budget).
template <int HJ>
__device__ __forceinline__ void h_gemm_pair(const f16* __restrict__ Hf,
                                            const f16* __restrict__ hA,
                                            const f16* __restrict__ hB,
                                            int lane8, int t,
                                            const f16x8 (&ipA)[2][2],
                                            const f16x8 (&ipB)[2][2],
                                            f32x16 (&acc)[2][2])
{
    acc[0][0] = zero16(); acc[0][1] = zero16();
    acc[1][0] = zero16(); acc[1][1] = zero16();
    const f16* Wp = Hf + lane8;
    f16x8 wb[2][4];
    f16 sA[2][4], sB[2][4];
#pragma unroll
    for (int ph = 0; ph < 2; ++ph)
#pragma unroll
        for (int r = 0; r < 2; ++r) {
            int j = ph * 2 + r;
            wb[ph][2*r]   = *(const f16x8*)(Wp + j * 1024);
            wb[ph][2*r+1] = *(const f16x8*)(Wp + j * 1024 + 512);
            sA[ph][2*r]   = hA[j * HSTR + t];
            sA[ph][2*r+1] = hA[j * HSTR + 32 + t];
            sB[ph][2*r]   = hB[j * HSTR + t];
            sB[ph][2*r+1] = hB[j * HSTR + 32 + t];
        }
    for (int jj = 0; jj < HJ; jj += 4) {
#pragma unroll
        for (int ph = 0; ph < 2; ++ph) {
            int jn = jj + 4 + ph * 2;
            if (jn > HJ - 2) jn = HJ - 2;                  // clamped refill
            f16x8 c0 = wb[ph][0], c1 = wb[ph][1], c2 = wb[ph][2], c3 = wb[ph][3];
            f16 a0 = sA[ph][0], a1 = sA[ph][1], a2 = sA[ph][2], a3 = sA[ph][3];
            f16 b0 = sB[ph][0], b1 = sB[ph][1], b2 = sB[ph][2], b3 = sB[ph][3];
#pragma unroll
            for (int r = 0; r < 2; ++r) {
                int j = jn + r;
                wb[ph][2*r]   = *(const f16x8*)(Wp + j * 1024);
                wb[ph][2*r+1] = *(const f16x8*)(Wp + j * 1024 + 512);
                sA[ph][2*r]   = hA[j * HSTR + t];
                sA[ph][2*r+1] = hA[j * HSTR + 32 + t];
                sB[ph][2*r]   = hB[j * HSTR + t];
                sB[ph][2*r+1] = hB[j * HSTR + 32 + t];
            }
            // consume j0 of the pair
            acc[0][0] = __builtin_amdgcn_mfma_f32_32x32x16_f16(c0, ipA[0][0] * a0, acc[0][0], 0, 0, 0);
            acc[0][1] = __builtin_amdgcn_mfma_f32_32x32x16_f16(c0, ipA[0][1] * a1, acc[0][1], 0, 0, 0);
            acc[1][0] = __builtin_amdgcn_mfma_f32_32x32x16_f16(c0, ipB[0][0] * b0, acc[1][0], 0, 0, 0);
            acc[1][1] = __builtin_amdgcn_mfma_f32_32x32x16_f16(c0, ipB[0][1] * b1, acc[1][1], 0, 0, 0);
            acc[0][0] = __builtin_amdgcn_mfma_f32_32x32x16_f16(c1, ipA[1][0] * a0, acc[0][0], 0, 0, 0);
            acc[0][1] = __builtin_amdgcn_mfma_f32_32x32x16_f16(c1, ipA[1][1] * a1, acc[0][1], 0, 0, 0);
            acc[1][0] = __builtin_amdgcn_mfma_f32_32x32x16_f16(c1, ipB[1][0] * b0, acc[1][0], 0, 0, 0);
            acc[1][1] = __builtin_amdgcn_mfma_f32_32x32x16_f16(c1, ipB[1][1] * b1, acc[1][1], 0, 0, 0);
            // consume j1
            acc[0][0] = __builtin_amdgcn_mfma_f32_32x32x16_f16(c2, ipA[0][0] * a2, acc[0][0], 0, 0, 0);
            acc[0][1] = __builtin_amdgcn_mfma_f32_32x32x16_f16(c2, ipA[0][1] * a3, acc[0][1], 0, 0, 0);
            acc[1][0] = __builtin_amdgcn_mfma_f32_32x32x16_f16(c2, ipB[0][0] * b2, acc[1][0], 0, 0, 0);
            acc[1][1] = __builtin_amdgcn_mfma_f32_32x32x16_f16(c2, ipB[0][1] * b3, acc[1][1], 0, 0, 0);
            acc[0][0] = __builtin_amdgcn_mfma_f32_32x32x16_f16(c3, ipA[1][0] * a2, acc[0][0], 0, 0, 0);
            acc[0][1] = __builtin_amdgcn_mfma_f32_32x32x16_f16(c3, ipA[1][1] * a3, acc[0][1], 0, 0, 0);
            acc[1][0] = __builtin_amdgcn_mfma_f32_32x32x16_f16(c3, ipB[1][0] * b2, acc[1][0], 0, 0, 0);
            acc[1][1] = __builtin_amdgcn_mfma_f32_32x32x16_f16(c3, ipB[1][1] * b3, acc[1][1], 0, 0, 0);
        }
    }
}

__device__ __forceinline__ void load_bias(const float* __restrict__ bl,
                                          float (&bve)[16], int g, int q)
{
#pragma unroll
    for (int r = 0; r < 16; ++r)
        bve[r] = bl[g * 32 + (r & 3) + 8 * (r >> 2) + 4 * q];
}

__device__ __forceinline__ void epi_h_pair(const f32x16 (&acc)[2][2],
                                           f16* __restrict__ hA, f16* __restrict__ hB,
                                           const float (&bve)[16], int g, int t, int q)
{
#pragma unroll
    for (int r = 0; r < 16; ++r) {
        int row = g * 32 + (r & 3) + 8 * (r >> 2) + 4 * q;
        hA[row * HSTR + t]      = (f16)(acc[0][0][r] + bve[r]);
        hA[row * HSTR + 32 + t] = (f16)(acc[0][1][r] + bve[r]);
        hB[row * HSTR + t]      = (f16)(acc[1][0][r] + bve[r]);
        hB[row * HSTR + 32 + t] = (f16)(acc[1][1][r] + bve[r]);
    }
}

// =================== Kernel 1: h-chain + p-vectors =========================
__global__ void __launch_bounds__(256, 2)
cin_h(const float* __restrict__ inp, const f16* __restrict__ Wf,
      f16* __restrict__ pW,
      const float* __restrict__ b0v, const float* __restrict__ b1v)
{
    // LDS (55296 B): inpL [4][32*HSTR] (18432) | hL [4][64*HSTR] (36864)
    __shared__ __attribute__((aligned(16))) char smem[55296];
    f16* inpL = (f16*)smem;
    f16* hL   = (f16*)(smem + 18432);

    const int tid   = threadIdx.x;
    const int w     = tid >> 6;
    const int lane  = tid & 63;
    const int t     = lane & 31;
    const int q     = lane >> 5;
    const int lane8 = lane * 8;
    const int g     = w & 1;          // row-half for h-GEMM
    const int bp    = w >> 1;         // batch-pair index
    const int bA    = bp * 2, bB = bp * 2 + 1;
    const int b0i   = blockIdx.x * 4;

    // Stage: wave w loads full batch w (coalesced f32x4 -> f16x4, stride HSTR).
    {
        const float* ib = inp + (size_t)(b0i + w) * 2048;
        f16* dst = inpL + w * 32 * HSTR;
#pragma unroll
        for (int it = 0; it < 8; ++it) {
            int idx = it * 256 + lane * 4;
            f32x4 v = *(const f32x4*)(ib + idx);
            int z = idx >> 6, k = idx & 63;
            f16x4 h4;
            h4[0] = (f16)v[0]; h4[1] = (f16)v[1]; h4[2] = (f16)v[2]; h4[3] = (f16)v[3];
            *(f16x4*)(dst + z * HSTR + k) = h4;
        }
    }
    f16* pMy = pW + (size_t)(b0i + w) * PBS;
    // p0 (layer 0, h0 = inp): wave-private, before the barrier.
    p_chunk_g(inpL + w * 32 * HSTR, inpL + w * 32 * HSTR, pMy, t, q);
    __syncthreads();                                   // B0: inpL ready

    // ip frags for both batches of this wave's pair:
    // ip[kq][nh][i] = inp[b][z=kq*16+q*8+i][nh*32+t]
    f16x8 ipA[2][2], ipB[2][2];
#pragma unroll
    for (int kq = 0; kq < 2; ++kq)
#pragma unroll
        for (int nh = 0; nh < 2; ++nh) {
            f16x8 va, vb;
            const f16* sa = inpL + bA * 32 * HSTR;
            const f16* sb = inpL + bB * 32 * HSTR;
#pragma unroll
            for (int i = 0; i < 8; ++i) {
                int off = (kq * 16 + q * 8 + i) * HSTR + nh * 32 + t;
                va[i] = sa[off];
                vb[i] = sb[off];
            }
            ipA[kq][nh] = va; ipB[kq][nh] = vb;
        }

    const f16* H0 = Wf;
    const f16* H1 = Wf + 131072;
    f16* hLA = hL + bA * 64 * HSTR;
    f16* hLB = hL + bB * 64 * HSTR;
    f32x16 acc[2][2];
    float bve[16];

    // ---- Layer 0 h-GEMM (HJ=32) ----
    h_gemm_pair<32>(H0 + g * 64 * 512, inpL + bA * 32 * HSTR, inpL + bB * 32 * HSTR,
                    lane8, t, ipA, ipB, acc);
    load_bias(b0v, bve, g, q);
    epi_h_pair(acc, hLA, hLB, bve, g, t, q);
    __syncthreads();                                   // B1: h1 ready

    // p1 (wave w <-> batch w), rows 0..31 and 32..63
    {
        const f16* hb = hL + w * 64 * HSTR;
        const f16* ib = inpL + w * 32 * HSTR;
        p_chunk_g(hb,             ib, pMy + 1024,      t, q);
        p_chunk_g(hb + 32 * HSTR, ib, pMy + 1024 + 1024, t, q);
    }
    // ---- Layer 1 h-GEMM (HJ=64) ----
    h_gemm_pair<64>(H1 + g * 128 * 512, hLA, hLB, lane8, t, ipA, ipB, acc);
    load_bias(b1v, bve, g, q);
    __syncthreads();                                   // B2: all h1 reads done
    epi_h_pair(acc, hLA, hLB, bve, g, t, q);           // overwrite h1 -> h2
    __syncthreads();                                   // B3: h2 ready

    // p2
    {
        const f16* hb = hL + w * 64 * HSTR;
        const f16* ib = inpL + w * 32 * HSTR;
        p_chunk_g(hb,             ib, pMy + 3072,      t, q);
        p_chunk_g(hb + 32 * HSTR, ib, pMy + 3072 + 1024, t, q);
    }
}

// =================== Kernel 2: out GEMMs (N = batch) =======================
// Block: one region x 32-batch group.  Waves: MW m-tiles x KW k-parts.
template <int M, int K, int KW>
__device__ __forceinline__ void o_region(const f16* __restrict__ Of,
                                         const f16* __restrict__ pWr,  // + poff
                                         const float* __restrict__ biasp,
                                         float* __restrict__ out,
                                         f16* __restrict__ Pt, float* __restrict__ rP,
                                         int bg, int colbase, int tid)
{
    constexpr int KKr = K / 16;
    constexpr int NC  = K / CK;
    constexpr int S   = (CK / KW) / 16;
    const int w = tid >> 6, lane = tid & 63, t = lane & 31, q = lane >> 5;
    const int lane8 = lane * 8;
    const int mi = (KW == 2) ? (w & 1) : w;
    const int ki = (KW == 2) ? (w >> 1) : 0;

    f32x16 acc = zero16();
    for (int c = 0; c < NC; ++c) {
        int c0 = c * CK;
        // stage P-chunk: 32 batches x 512 c (coalesced global, f16x8)
#pragma unroll
        for (int it = 0; it < 8; ++it) {
            int idx = it * 2048 + tid * 8;
            int row = idx >> 9, col = idx & 511;
            f16x8 v = *(const f16x8*)(pWr + (size_t)(bg * 32 + row) * PBS + c0 + col);
            *(f16x8*)(Pt + row * PT + col) = v;
        }
        __syncthreads();
        const int lc0 = ki * (CK / KW);
        const f16* Ap = Of + (size_t)(mi * KKr + (c0 + lc0) / 16) * 512 + lane8;
        const f16* Bp = Pt + t * PT + lc0 + q * 8;
        f16x8 a0 = *(const f16x8*)(Ap);
        f16x8 a1 = *(const f16x8*)(Ap + 512);
#pragma unroll
        for (int s = 0; s < S; ++s) {
            f16x8 cur = a0; a0 = a1;
            int sn = s + 2 < S ? s + 2 : S - 1;
            a1 = *(const f16x8*)(Ap + sn * 512);
            f16x8 b = *(const f16x8*)(Bp + s * 16);
            acc = __builtin_amdgcn_mfma_f32_32x32x16_f16(cur, b, acc, 0, 0, 0);
        }
        __syncthreads();
    }
    // partials -> rP[ki][n=col][m]
#pragma unroll
    for (int r = 0; r < 16; ++r) {
        int m = mi * 32 + (r & 3) + 8 * (r >> 2) + 4 * q;
        rP[(ki * 32 + t) * M + m] = acc[r];
    }
    __syncthreads();
    // coalesced output: out[batch][colbase + o] = sum partials + 64*bias[o]
    constexpr int TOT = 32 * M / 4;
#pragma unroll
    for (int it = 0; it < TOT / 256; ++it) {
        int idx = (it * 256 + tid) * 4;
        int n = idx / M, o = idx % M;
        f32x4 v = *(const f32x4*)(rP + n * M + o);
        if (KW == 2) {
            f32x4 v2 = *(const f32x4*)(rP + (32 + n) * M + o);
            v[0] += v2[0]; v[1] += v2[1]; v[2] += v2[2]; v[3] += v2[3];
        }
        f32x4 bb = *(const f32x4*)(biasp + o);
        f32x4 ov;
        ov[0] = v[0] + 64.0f * bb[0]; ov[1] = v[1] + 64.0f * bb[1];
        ov[2] = v[2] + 64.0f * bb[2]; ov[3] = v[3] + 64.0f * bb[3];
        *(f32x4*)(out + (size_t)(bg * 32 + n) * 256 + colbase + o) = ov;
    }
}

__global__ void __launch_bounds__(256, 2)
cin_out(const f16* __restrict__ Wf, const f16* __restrict__ pW,
        const float* __restrict__ b0v, const float* __restrict__ b1v,
        const float* __restrict__ b2v, float* __restrict__ out)
{
    // LDS: Pt 32*PT*2 = 33280 | rP 16384  -> 49664 B
    __shared__ __attribute__((aligned(16))) char smem[49664];
    f16*   Pt = (f16*)smem;
    float* rP = (float*)(smem + 33280);
    const int tid = threadIdx.x;
    const int r  = blockIdx.x >> 6;     // region
    const int bg = blockIdx.x & 63;     // 32-batch group
    if (r == 0)
        o_region<64, 1024, 2>(Wf + 65536,  pW,        b0v + 64, out, Pt, rP, bg, 0,   tid);
    else if (r == 1)
        o_region<64, 2048, 2>(Wf + 262144, pW + 1024, b1v + 64, out, Pt, rP, bg, 64,  tid);
    else
        o_region<128, 2048, 1>(Wf + 393216, pW + 3072, b2v,      out, Pt, rP, bg, 128, tid);
}

extern "C" void kernel_launch(void* const* d_in, const int* in_sizes, int n_in,
                              void* d_out, int out_size, void* d_ws, size_t ws_size,
                              hipStream_t stream)
{
    const float* inp = (const float*)d_in[0];
    const float* W0  = (const float*)d_in[1];
    const float* b0  = (const float*)d_in[2];
    const float* W1  = (const float*)d_in[3];
    const float* b1  = (const float*)d_in[4];
    const float* W2  = (const float*)d_in[5];
    const float* b2  = (const float*)d_in[6];
    float* out = (float*)d_out;

    f16* Wf = (f16*)d_ws;             // 655360 f16 = 1.25 MB fragment-ordered
    f16* pW = Wf + 655360;            // 2048 * 5120 f16 = 20 MB p-vectors

    prep_frag<<<320, 256, 0, stream>>>(W0, W1, W2, Wf);
    cin_h<<<512, 256, 0, stream>>>(inp, Wf, pW, b0, b1);
    cin_out<<<192, 256, 0, stream>>>(Wf, pW, b0, b1, b2, out);
}

// Round 9
// 147.569 us; speedup vs baseline: 2.0479x; 1.0036x over previous
//
#include <hip/hip_runtime.h>

// xDeepFM CIN, MI355X (gfx950) — two-kernel split, R9.
// cin_h: per-batch h-chain + p-vectors (p_l[c=j*32+z] = sum_k h_l[j,k] inp[z,k])
//   2 batches/block, grid 1024 -> 4 blocks/CU.  Wave = (row-half g, col-half kh).
//   inp staged straight into hL rows 0..31 (it IS h0); p-GEMM B-frags kept in
//   registers for the whole kernel (h1 overwrites the inp rows).  LDS 18 KB.
// cin_out: out columns as real GEMMs D[o, batch] = W_o @ p, N=32 batches.
//   No LDS staging: B-frags read directly from global, depth-4 prefetch,
//   256 blocks, one barrier (partial reduce).

typedef _Float16 f16;
typedef _Float16 f16x4 __attribute__((ext_vector_type(4)));
typedef _Float16 f16x8 __attribute__((ext_vector_type(8)));
typedef float f32x4 __attribute__((ext_vector_type(4)));
typedef float f32x16 __attribute__((ext_vector_type(16)));

#define HSTR 72      // h LDS row stride (f16): 144B = 9*16B, b128-aligned
#define PBS  5120    // pW per-batch stride (f16): p0(1024)+p1(2048)+p2(2048)

__device__ __forceinline__ f32x16 zero16() {
    f32x16 v;
#pragma unroll
    for (int i = 0; i < 16; ++i) v[i] = 0.0f;
    return v;
}

// ---------------- prep: W (fp32 row-major) -> f16 fragment-ordered ----------
// Fragment (mc, kk) = 512 f16; element lane*8+i =
//   W[rbase + mc*32 + (lane&31)][kk*16 + (lane>>5)*8 + i]
// Regions (f16 offsets): H0@0 (W0 r0..63, KK=64) | O0@65536 (W0 r64..127) |
// H1@131072 (W1 r0..63, KK=128) | O1@262144 (W1 r64..127) | O2@393216 (W2 all).
__global__ void __launch_bounds__(256)
prep_frag(const float* __restrict__ W0, const float* __restrict__ W1,
          const float* __restrict__ W2, f16* __restrict__ dst)
{
    int g = (blockIdx.x * 256 + threadIdx.x) * 8;    // grid = 320
    const float* src; int base, KK, rbase;
    if (g < 65536)       { src = W0; base = 0;      KK = 64;  rbase = 0;  }
    else if (g < 131072) { src = W0; base = 65536;  KK = 64;  rbase = 64; }
    else if (g < 262144) { src = W1; base = 131072; KK = 128; rbase = 0;  }
    else if (g < 393216) { src = W1; base = 262144; KK = 128; rbase = 64; }
    else                 { src = W2; base = 393216; KK = 128; rbase = 0;  }
    int local = g - base;
    int frag  = local >> 9;
    int lane  = (local >> 3) & 63;
    int kk    = frag % KK;
    int mc    = frag / KK;
    int row   = rbase + mc * 32 + (lane & 31);
    int col   = kk * 16 + (lane >> 5) * 8;
    int IC    = KK * 16;
    const float* s = src + (size_t)row * IC + col;
    f16x8 o;
#pragma unroll
    for (int i = 0; i < 8; ++i) o[i] = (f16)s[i];
    *(f16x8*)(dst + g) = o;
}

// ---- p-chunk: p rows [jb, jb+32) of one batch -> global (M=32,N=32,K=64) ---
// B-frags (inp) come from registers; A-frags from h rows in LDS.
__device__ __forceinline__ void p_chunk(const f16* __restrict__ hrows,
                                        const f16x8 (&pB)[4],
                                        f16* __restrict__ pdst, int t, int q)
{
    f32x16 acc = zero16();
#pragma unroll
    for (int s = 0; s < 4; ++s) {
        f16x8 a = *(const f16x8*)(hrows + t * HSTR + s * 16 + q * 8);
        acc = __builtin_amdgcn_mfma_f32_32x32x16_f16(a, pB[s], acc, 0, 0, 0);
    }
#pragma unroll
    for (int r = 0; r < 16; ++r) {
        int row = (r & 3) + 8 * (r >> 2) + 4 * q;
        pdst[row * 32 + t] = (f16)acc[r];
    }
}

// ---- h-GEMM: rows [g*32,+32), cols [kh*32,+32), BOTH batches ---------------
// Per j: 2 W-frag loads feed 4 MFMAs.  Ping-pong holds 2 j-pairs (depth ~2
// phases = 8 loads in flight).
template <int HJ>
__device__ __forceinline__ void h_gemm2(const f16* __restrict__ Hf,
                                        const f16* __restrict__ h0,
                                        const f16* __restrict__ h1,
                                        int lane8, int khOff,
                                        const f16x8 (&ip)[2][2],
                                        f32x16 (&acc)[2])
{
    acc[0] = zero16(); acc[1] = zero16();
    const f16* Wp = Hf + lane8;
    f16x8 wb[2][4];     // [phase][jr*2+kq]
    f16   sc[2][4];     // [phase][jr*2+b]
#pragma unroll
    for (int ph = 0; ph < 2; ++ph)
#pragma unroll
        for (int jr = 0; jr < 2; ++jr) {
            int j = ph * 2 + jr;
            wb[ph][jr*2+0] = *(const f16x8*)(Wp + (j * 2 + 0) * 512);
            wb[ph][jr*2+1] = *(const f16x8*)(Wp + (j * 2 + 1) * 512);
            sc[ph][jr*2+0] = h0[j * HSTR + khOff];
            sc[ph][jr*2+1] = h1[j * HSTR + khOff];
        }
    for (int jj = 0; jj < HJ; jj += 4) {
#pragma unroll
        for (int ph = 0; ph < 2; ++ph) {
            // consume phase ph (j = jj+ph*2, jj+ph*2+1)
#pragma unroll
            for (int jr = 0; jr < 2; ++jr) {
                f16x8 w0 = wb[ph][jr*2+0], w1 = wb[ph][jr*2+1];
                f16 s0 = sc[ph][jr*2+0], s1 = sc[ph][jr*2+1];
                acc[0] = __builtin_amdgcn_mfma_f32_32x32x16_f16(w0, ip[0][0] * s0, acc[0], 0, 0, 0);
                acc[1] = __builtin_amdgcn_mfma_f32_32x32x16_f16(w0, ip[1][0] * s1, acc[1], 0, 0, 0);
                acc[0] = __builtin_amdgcn_mfma_f32_32x32x16_f16(w1, ip[0][1] * s0, acc[0], 0, 0, 0);
                acc[1] = __builtin_amdgcn_mfma_f32_32x32x16_f16(w1, ip[1][1] * s1, acc[1], 0, 0, 0);
            }
            // refill phase ph from j = jn, jn+1 (clamped; tail re-reads)
            int jn = jj + 4 + ph * 2;
            if (jn > HJ - 2) jn = HJ - 2;
#pragma unroll
            for (int jr = 0; jr < 2; ++jr) {
                int j = jn + jr;
                wb[ph][jr*2+0] = *(const f16x8*)(Wp + (j * 2 + 0) * 512);
                wb[ph][jr*2+1] = *(const f16x8*)(Wp + (j * 2 + 1) * 512);
                sc[ph][jr*2+0] = h0[j * HSTR + khOff];
                sc[ph][jr*2+1] = h1[j * HSTR + khOff];
            }
        }
    }
}

__device__ __forceinline__ void load_bias(const float* __restrict__ bl,
                                          float (&bve)[16], int g, int q)
{
#pragma unroll
    for (int r = 0; r < 16; ++r)
        bve[r] = bl[g * 32 + (r & 3) + 8 * (r >> 2) + 4 * q];
}

// Write h_{l+1} rows [g*32,+32), cols khOff half, both batches.
__device__ __forceinline__ void epi2(const f32x16 (&acc)[2], f16* __restrict__ hL,
                                     const float (&bve)[16], int g, int khOff,
                                     int t, int q)
{
#pragma unroll
    for (int r = 0; r < 16; ++r) {
        int row = g * 32 + (r & 3) + 8 * (r >> 2) + 4 * q;
        hL[row * HSTR + khOff]              = (f16)(acc[0][r] + bve[r]);
        hL[64 * HSTR + row * HSTR + khOff]  = (f16)(acc[1][r] + bve[r]);
    }
}

// =================== Kernel 1: h-chain + p-vectors =========================
__global__ void __launch_bounds__(256, 4)
cin_h(const float* __restrict__ inp, const f16* __restrict__ Wf,
      f16* __restrict__ pW,
      const float* __restrict__ b0v, const float* __restrict__ b1v)
{
    __shared__ __attribute__((aligned(16))) f16 hL[2 * 64 * HSTR];  // 18432 B

    const int tid   = threadIdx.x;
    const int w     = tid >> 6;
    const int lane  = tid & 63;
    const int t     = lane & 31;
    const int q     = lane >> 5;
    const int lane8 = lane * 8;
    const int kh    = w & 1;          // col-half
    const int g     = w >> 1;         // row-half
    const int khOff = kh * 32 + t;
    const int b0i   = blockIdx.x * 2;

    // Stage: 2 batches x 32 z-rows of inp (f32 coalesced) -> hL rows 0..31.
#pragma unroll
    for (int it = 0; it < 4; ++it) {
        int idx = it * 1024 + tid * 4;
        int b = idx >> 11, rem = idx & 2047;
        int z = rem >> 6, k = rem & 63;
        f32x4 v = *(const f32x4*)(inp + (size_t)(b0i + b) * 2048 + rem);
        f16x4 h4;
        h4[0] = (f16)v[0]; h4[1] = (f16)v[1]; h4[2] = (f16)v[2]; h4[3] = (f16)v[3];
        *(f16x4*)(hL + b * 64 * HSTR + z * HSTR + k) = h4;
    }
    __syncthreads();                                   // B0: h0 (=inp) ready

    // ip[b][kq][i] = inp[b][z=kq*16+q*8+i][khOff]  (B-frag bases for h-GEMM)
    f16x8 ip[2][2];
#pragma unroll
    for (int b = 0; b < 2; ++b)
#pragma unroll
        for (int kq = 0; kq < 2; ++kq) {
            f16x8 v;
            const f16* src = hL + b * 64 * HSTR;
#pragma unroll
            for (int i = 0; i < 8; ++i)
                v[i] = src[(kq * 16 + q * 8 + i) * HSTR + khOff];
            ip[b][kq] = v;
        }
    // pB[s][i] = inp[kh][z=t][k=s*16+q*8+i]  — p-GEMM B-frags, live all kernel
    f16x8 pB[4];
#pragma unroll
    for (int s = 0; s < 4; ++s)
        pB[s] = *(const f16x8*)(hL + kh * 64 * HSTR + t * HSTR + s * 16 + q * 8);

    f16* pMy = pW + (size_t)(b0i + kh) * PBS;
    const f16* H0 = Wf;
    const f16* H1 = Wf + 131072;
    f32x16 acc[2];
    float bve[16];

    // ---- Layer 0 ----
    if (g == 0)                                       // p0: 2 chunks, g==0 waves
        p_chunk(hL + kh * 64 * HSTR, pB, pMy, t, q);
    h_gemm2<32>(H0 + g * 64 * 512, hL, hL + 64 * HSTR, lane8, khOff, ip, acc);
    load_bias(b0v, bve, g, q);
    __syncthreads();                                   // B1: all h0 reads done
    epi2(acc, hL, bve, g, khOff, t, q);                // h1 overwrites rows 0..31 too
    __syncthreads();                                   // B2: h1 ready

    // ---- Layer 1 ----
    p_chunk(hL + kh * 64 * HSTR + g * 32 * HSTR, pB, pMy + 1024 + g * 1024, t, q);
    h_gemm2<64>(H1 + g * 128 * 512, hL, hL + 64 * HSTR, lane8, khOff, ip, acc);
    load_bias(b1v, bve, g, q);
    __syncthreads();                                   // B3: all h1 reads done
    epi2(acc, hL, bve, g, khOff, t, q);                // h1 -> h2 in place
    __syncthreads();                                   // B4: h2 ready

    p_chunk(hL + kh * 64 * HSTR + g * 32 * HSTR, pB, pMy + 3072 + g * 1024, t, q);
}

// =================== Kernel 2: out GEMMs (N = batch) =======================
// Block = (32-batch group) x (M=64 region).  Waves (mi, ki): m-tile x K-half.
// A coalesced frag loads; B-frags direct from global (lane t <-> batch row).
template <int S>
__device__ __forceinline__ void o_tile(const f16* __restrict__ Of,
                                       const f16* __restrict__ pBase,
                                       const float* __restrict__ biasp,
                                       float* __restrict__ out,
                                       float* __restrict__ rP,
                                       int bg, int colbase, int tid)
{
    const int w = tid >> 6, lane = tid & 63, t = lane & 31, q = lane >> 5;
    const int lane8 = lane * 8;
    const int mi = w & 1, ki = w >> 1;
    const f16* Ap = Of + (size_t)(mi * 2 * S + ki * S) * 512 + lane8;
    const f16* Bp = pBase + (size_t)(bg * 32 + t) * PBS + ki * S * 16 + q * 8;

    f32x16 acc = zero16();
    f16x8 af[4], bf[4];
#pragma unroll
    for (int i = 0; i < 4; ++i) {
        af[i] = *(const f16x8*)(Ap + i * 512);
        bf[i] = *(const f16x8*)(Bp + i * 16);
    }
#pragma unroll 4
    for (int s = 0; s < S; ++s) {
        int idx = s & 3;
        f16x8 a = af[idx], b = bf[idx];
        int sn = s + 4 < S ? s + 4 : S - 1;            // clamped refill
        af[idx] = *(const f16x8*)(Ap + sn * 512);
        bf[idx] = *(const f16x8*)(Bp + sn * 16);
        acc = __builtin_amdgcn_mfma_f32_32x32x16_f16(a, b, acc, 0, 0, 0);
    }
#pragma unroll
    for (int r = 0; r < 16; ++r) {
        int m = mi * 32 + (r & 3) + 8 * (r >> 2) + 4 * q;
        rP[(ki * 32 + t) * 64 + m] = acc[r];
    }
    __syncthreads();
#pragma unroll
    for (int it = 0; it < 2; ++it) {
        int idx4 = (it * 256 + tid) * 4;
        int n = idx4 >> 6, o = idx4 & 63;
        f32x4 v0 = *(const f32x4*)(rP + n * 64 + o);
        f32x4 v1 = *(const f32x4*)(rP + (32 + n) * 64 + o);
        f32x4 bb = *(const f32x4*)(biasp + o);
        f32x4 ov;
        ov[0] = v0[0] + v1[0] + 64.0f * bb[0];
        ov[1] = v0[1] + v1[1] + 64.0f * bb[1];
        ov[2] = v0[2] + v1[2] + 64.0f * bb[2];
        ov[3] = v0[3] + v1[3] + 64.0f * bb[3];
        *(f32x4*)(out + (size_t)(bg * 32 + n) * 256 + colbase + o) = ov;
    }
}

__global__ void __launch_bounds__(256, 2)
cin_out(const f16* __restrict__ Wf, const f16* __restrict__ pW,
        const float* __restrict__ b0v, const float* __restrict__ b1v,
        const float* __restrict__ b2v, float* __restrict__ out)
{
    __shared__ __attribute__((aligned(16))) float rP[2 * 32 * 64];  // 16 KB
    const int tid = threadIdx.x;
    const int r  = blockIdx.x & 3;      // region
    const int bg = blockIdx.x >> 2;     // 32-batch group (64 of them)
    if (r == 0)
        o_tile<32>(Wf + 65536,  pW,        b0v + 64, out, rP, bg, 0,   tid);
    else if (r == 1)
        o_tile<64>(Wf + 262144, pW + 1024, b1v + 64, out, rP, bg, 64,  tid);
    else if (r == 2)
        o_tile<64>(Wf + 393216, pW + 3072, b2v,      out, rP, bg, 128, tid);
    else
        o_tile<64>(Wf + 524288, pW + 3072, b2v + 64, out, rP, bg, 192, tid);
}

extern "C" void kernel_launch(void* const* d_in, const int* in_sizes, int n_in,
                              void* d_out, int out_size, void* d_ws, size_t ws_size,
                              hipStream_t stream)
{
    const float* inp = (const float*)d_in[0];
    const float* W0  = (const float*)d_in[1];
    const float* b0  = (const float*)d_in[2];
    const float* W1  = (const float*)d_in[3];
    const float* b1  = (const float*)d_in[4];
    const float* W2  = (const float*)d_in[5];
    const float* b2  = (const float*)d_in[6];
    float* out = (float*)d_out;

    f16* Wf = (f16*)d_ws;             // 655360 f16 = 1.25 MB fragment-ordered
    f16* pW = Wf + 655360;            // 2048 * 5120 f16 = 20 MB p-vectors

    prep_frag<<<320, 256, 0, stream>>>(W0, W1, W2, Wf);
    cin_h<<<1024, 256, 0, stream>>>(inp, Wf, pW, b0, b1);
    cin_out<<<256, 256, 0, stream>>>(Wf, pW, b0, b1, b2, out);
}

// Round 10
// 138.346 us; speedup vs baseline: 2.1844x; 1.0667x over previous
//
#include <hip/hip_runtime.h>

// xDeepFM CIN, MI355X (gfx950) — two-kernel split, R10.
// cin_h: per-batch h-chain + p-vectors.  4 batches/block, wave = (row-half g,
//   batch-pair bp): one W-fragment pair feeds 8 MFMAs (258 SIMD-cyc) > ~200cyc
//   L2 latency, so the load latency hides under the MFMA window structurally
//   (R8/R9 post-mortem: 4-MFMA windows < latency => stuck at 37% MfmaUtil).
//   W traffic halves to 96 KB/batch -> TCP ~10us/CU << 21us MFMA floor.
// cin_out: out columns as real GEMMs D[o, batch] = W_o @ p, N=32 batches,
//   B-frags direct from global, depth-4 prefetch (unchanged from R9).

typedef _Float16 f16;
typedef _Float16 f16x4 __attribute__((ext_vector_type(4)));
typedef _Float16 f16x8 __attribute__((ext_vector_type(8)));
typedef float f32x4 __attribute__((ext_vector_type(4)));
typedef float f32x16 __attribute__((ext_vector_type(16)));

#define HSTR 72      // h LDS row stride (f16): 144B = 9*16B, b128-aligned
#define PBS  5120    // pW per-batch stride (f16): p0(1024)+p1(2048)+p2(2048)

__device__ __forceinline__ f32x16 zero16() {
    f32x16 v;
#pragma unroll
    for (int i = 0; i < 16; ++i) v[i] = 0.0f;
    return v;
}

// ---------------- prep: W (fp32 row-major) -> f16 fragment-ordered ----------
// Fragment (mc, kk) = 512 f16; element lane*8+i =
//   W[rbase + mc*32 + (lane&31)][kk*16 + (lane>>5)*8 + i]
// Regions (f16 offsets): H0@0 (W0 r0..63, KK=64) | O0@65536 (W0 r64..127) |
// H1@131072 (W1 r0..63, KK=128) | O1@262144 (W1 r64..127) | O2@393216 (W2 all).
__global__ void __launch_bounds__(256)
prep_frag(const float* __restrict__ W0, const float* __restrict__ W1,
          const float* __restrict__ W2, f16* __restrict__ dst)
{
    int g = (blockIdx.x * 256 + threadIdx.x) * 8;    // grid = 320
    const float* src; int base, KK, rbase;
    if (g < 65536)       { src = W0; base = 0;      KK = 64;  rbase = 0;  }
    else if (g < 131072) { src = W0; base = 65536;  KK = 64;  rbase = 64; }
    else if (g < 262144) { src = W1; base = 131072; KK = 128; rbase = 0;  }
    else if (g < 393216) { src = W1; base = 262144; KK = 128; rbase = 64; }
    else                 { src = W2; base = 393216; KK = 128; rbase = 0;  }
    int local = g - base;
    int frag  = local >> 9;
    int lane  = (local >> 3) & 63;
    int kk    = frag % KK;
    int mc    = frag / KK;
    int row   = rbase + mc * 32 + (lane & 31);
    int col   = kk * 16 + (lane >> 5) * 8;
    int IC    = KK * 16;
    const float* s = src + (size_t)row * IC + col;
    f16x8 o;
#pragma unroll
    for (int i = 0; i < 8; ++i) o[i] = (f16)s[i];
    *(f16x8*)(dst + g) = o;
}

// ---- p-chunk: p rows [jb, jb+32) of one batch -> global (M=32,N=32,K=64) ---
__device__ __forceinline__ void p_chunk(const f16* __restrict__ hrows,
                                        const f16x8 (&pB)[4],
                                        f16* __restrict__ pdst, int t, int q)
{
    f32x16 acc = zero16();
#pragma unroll
    for (int s = 0; s < 4; ++s) {
        f16x8 a = *(const f16x8*)(hrows + t * HSTR + s * 16 + q * 8);
        acc = __builtin_amdgcn_mfma_f32_32x32x16_f16(a, pB[s], acc, 0, 0, 0);
    }
#pragma unroll
    for (int r = 0; r < 16; ++r) {
        int row = (r & 3) + 8 * (r >> 2) + 4 * q;
        pdst[row * 32 + t] = (f16)acc[r];
    }
}

// ---- h-GEMM: rows [g*32,+32), ALL 64 cols, TWO batches ---------------------
// Per j: 2 W-frag loads feed 8 MFMAs (258 SIMD-cyc window > L2 latency).
// Ping-pong depth-2 (j, j+1 resident; refill j+2).
template <int HJ>
__device__ __forceinline__ void h_gemm4(const f16* __restrict__ Hf,
                                        const f16* __restrict__ h0,
                                        const f16* __restrict__ h1,
                                        int lane8, int t,
                                        const f16x8 (&ip)[2][2][2],   // [b][kq][nh]
                                        f32x16 (&acc)[2][2])          // [b][nh]
{
    acc[0][0] = zero16(); acc[0][1] = zero16();
    acc[1][0] = zero16(); acc[1][1] = zero16();
    const f16* Wp = Hf + lane8;
    f16x8 wf[2][2];   // [phase][kq]
    f16   sc[2][4];   // [phase][b*2+nh]
#pragma unroll
    for (int ph = 0; ph < 2; ++ph) {
        wf[ph][0] = *(const f16x8*)(Wp + (ph * 2 + 0) * 512);
        wf[ph][1] = *(const f16x8*)(Wp + (ph * 2 + 1) * 512);
        sc[ph][0] = h0[ph * HSTR + t];
        sc[ph][1] = h0[ph * HSTR + 32 + t];
        sc[ph][2] = h1[ph * HSTR + t];
        sc[ph][3] = h1[ph * HSTR + 32 + t];
    }
    for (int jj = 0; jj < HJ; jj += 2) {
#pragma unroll
        for (int ph = 0; ph < 2; ++ph) {
            f16x8 w0 = wf[ph][0], w1 = wf[ph][1];
            f16 s00 = sc[ph][0], s01 = sc[ph][1];
            f16 s10 = sc[ph][2], s11 = sc[ph][3];
            int jn = jj + ph + 2;
            if (jn > HJ - 1) jn = HJ - 1;              // clamped refill
            wf[ph][0] = *(const f16x8*)(Wp + (jn * 2 + 0) * 512);
            wf[ph][1] = *(const f16x8*)(Wp + (jn * 2 + 1) * 512);
            sc[ph][0] = h0[jn * HSTR + t];
            sc[ph][1] = h0[jn * HSTR + 32 + t];
            sc[ph][2] = h1[jn * HSTR + t];
            sc[ph][3] = h1[jn * HSTR + 32 + t];
            acc[0][0] = __builtin_amdgcn_mfma_f32_32x32x16_f16(w0, ip[0][0][0] * s00, acc[0][0], 0, 0, 0);
            acc[0][0] = __builtin_amdgcn_mfma_f32_32x32x16_f16(w1, ip[0][1][0] * s00, acc[0][0], 0, 0, 0);
            acc[0][1] = __builtin_amdgcn_mfma_f32_32x32x16_f16(w0, ip[0][0][1] * s01, acc[0][1], 0, 0, 0);
            acc[0][1] = __builtin_amdgcn_mfma_f32_32x32x16_f16(w1, ip[0][1][1] * s01, acc[0][1], 0, 0, 0);
            acc[1][0] = __builtin_amdgcn_mfma_f32_32x32x16_f16(w0, ip[1][0][0] * s10, acc[1][0], 0, 0, 0);
            acc[1][0] = __builtin_amdgcn_mfma_f32_32x32x16_f16(w1, ip[1][1][0] * s10, acc[1][0], 0, 0, 0);
            acc[1][1] = __builtin_amdgcn_mfma_f32_32x32x16_f16(w0, ip[1][0][1] * s11, acc[1][1], 0, 0, 0);
            acc[1][1] = __builtin_amdgcn_mfma_f32_32x32x16_f16(w1, ip[1][1][1] * s11, acc[1][1], 0, 0, 0);
        }
    }
}

__device__ __forceinline__ void load_bias(const float* __restrict__ bl,
                                          float (&bve)[16], int g, int q)
{
#pragma unroll
    for (int r = 0; r < 16; ++r)
        bve[r] = bl[g * 32 + (r & 3) + 8 * (r >> 2) + 4 * q];
}

// Write h_{l+1} rows [g*32,+32), all 64 cols, both batches.
__device__ __forceinline__ void epi4(const f32x16 (&acc)[2][2],
                                     f16* __restrict__ h0d, f16* __restrict__ h1d,
                                     const float (&bve)[16], int g, int t, int q)
{
#pragma unroll
    for (int r = 0; r < 16; ++r) {
        int row = g * 32 + (r & 3) + 8 * (r >> 2) + 4 * q;
        h0d[row * HSTR + t]      = (f16)(acc[0][0][r] + bve[r]);
        h0d[row * HSTR + 32 + t] = (f16)(acc[0][1][r] + bve[r]);
        h1d[row * HSTR + t]      = (f16)(acc[1][0][r] + bve[r]);
        h1d[row * HSTR + 32 + t] = (f16)(acc[1][1][r] + bve[r]);
    }
}

// =================== Kernel 1: h-chain + p-vectors =========================
__global__ void __launch_bounds__(256, 2)
cin_h(const float* __restrict__ inp, const f16* __restrict__ Wf,
      f16* __restrict__ pW,
      const float* __restrict__ b0v, const float* __restrict__ b1v)
{
    __shared__ __attribute__((aligned(16))) f16 hL[4 * 64 * HSTR];  // 36864 B

    const int tid   = threadIdx.x;
    const int w     = tid >> 6;
    const int lane  = tid & 63;
    const int t     = lane & 31;
    const int q     = lane >> 5;
    const int lane8 = lane * 8;
    const int bp    = w & 1;          // batch-pair (local batches bp*2, bp*2+1)
    const int g     = w >> 1;         // row-half
    const int b0i   = blockIdx.x * 4;

    // Stage: 4 batches x 32 z-rows of inp (f32 coalesced) -> hL rows 0..31.
#pragma unroll
    for (int it = 0; it < 8; ++it) {
        int idx = it * 1024 + tid * 4;
        int b = idx >> 11, rem = idx & 2047;
        int z = rem >> 6, k = rem & 63;
        f32x4 v = *(const f32x4*)(inp + (size_t)(b0i + b) * 2048 + rem);
        f16x4 h4;
        h4[0] = (f16)v[0]; h4[1] = (f16)v[1]; h4[2] = (f16)v[2]; h4[3] = (f16)v[3];
        *(f16x4*)(hL + b * 64 * HSTR + z * HSTR + k) = h4;
    }
    __syncthreads();                                   // B0: h0 (=inp) ready

    // ip[b][kq][nh][i] = inp[bp*2+b][z=kq*16+q*8+i][nh*32+t]
    f16x8 ip[2][2][2];
#pragma unroll
    for (int b = 0; b < 2; ++b) {
        const f16* src = hL + (bp * 2 + b) * 64 * HSTR;
#pragma unroll
        for (int kq = 0; kq < 2; ++kq)
#pragma unroll
            for (int nh = 0; nh < 2; ++nh) {
                f16x8 v;
#pragma unroll
                for (int i = 0; i < 8; ++i)
                    v[i] = src[(kq * 16 + q * 8 + i) * HSTR + nh * 32 + t];
                ip[b][kq][nh] = v;
            }
    }
    // pB[s][i] = inp[w][z=t][k=s*16+q*8+i] — p-GEMM B-frags (wave w <-> batch w)
    f16x8 pB[4];
#pragma unroll
    for (int s = 0; s < 4; ++s)
        pB[s] = *(const f16x8*)(hL + w * 64 * HSTR + t * HSTR + s * 16 + q * 8);

    f16* pMy = pW + (size_t)(b0i + w) * PBS;
    const f16* H0 = Wf;
    const f16* H1 = Wf + 131072;
    f16* hA = hL + (bp * 2) * 64 * HSTR;
    f16* hB = hL + (bp * 2 + 1) * 64 * HSTR;
    f32x16 acc[2][2];
    float bve[16];

    // ---- Layer 0 (HJ=32) ----
    p_chunk(hL + w * 64 * HSTR, pB, pMy, t, q);        // p0: wave w, batch w
    h_gemm4<32>(H0 + g * 64 * 512, hA, hB, lane8, t, ip, acc);
    load_bias(b0v, bve, g, q);
    __syncthreads();                                   // B1: all h0 reads done
    epi4(acc, hA, hB, bve, g, t, q);                   // h1 (rows 0..63)
    __syncthreads();                                   // B2: h1 ready

    // ---- Layer 1 (HJ=64) ----
    p_chunk(hL + w * 64 * HSTR,             pB, pMy + 1024, t, q);
    p_chunk(hL + w * 64 * HSTR + 32 * HSTR, pB, pMy + 2048, t, q);
    h_gemm4<64>(H1 + g * 128 * 512, hA, hB, lane8, t, ip, acc);
    load_bias(b1v, bve, g, q);
    __syncthreads();                                   // B3: all h1 reads done
    epi4(acc, hA, hB, bve, g, t, q);                   // h1 -> h2 in place
    __syncthreads();                                   // B4: h2 ready

    p_chunk(hL + w * 64 * HSTR,             pB, pMy + 3072, t, q);
    p_chunk(hL + w * 64 * HSTR + 32 * HSTR, pB, pMy + 4096, t, q);
}

// =================== Kernel 2: out GEMMs (N = batch) =======================
// Block = (32-batch group) x (M=64 region).  Waves (mi, ki): m-tile x K-half.
// A coalesced frag loads; B-frags direct from global (lane t <-> batch row).
template <int S>
__device__ __forceinline__ void o_tile(const f16* __restrict__ Of,
                                       const f16* __restrict__ pBase,
                                       const float* __restrict__ biasp,
                                       float* __restrict__ out,
                                       float* __restrict__ rP,
                                       int bg, int colbase, int tid)
{
    const int w = tid >> 6, lane = tid & 63, t = lane & 31, q = lane >> 5;
    const int lane8 = lane * 8;
    const int mi = w & 1, ki = w >> 1;
    const f16* Ap = Of + (size_t)(mi * 2 * S + ki * S) * 512 + lane8;
    const f16* Bp = pBase + (size_t)(bg * 32 + t) * PBS + ki * S * 16 + q * 8;

    f32x16 acc = zero16();
    f16x8 af[4], bf[4];
#pragma unroll
    for (int i = 0; i < 4; ++i) {
        af[i] = *(const f16x8*)(Ap + i * 512);
        bf[i] = *(const f16x8*)(Bp + i * 16);
    }
#pragma unroll 4
    for (int s = 0; s < S; ++s) {
        int idx = s & 3;
        f16x8 a = af[idx], b = bf[idx];
        int sn = s + 4 < S ? s + 4 : S - 1;            // clamped refill
        af[idx] = *(const f16x8*)(Ap + sn * 512);
        bf[idx] = *(const f16x8*)(Bp + sn * 16);
        acc = __builtin_amdgcn_mfma_f32_32x32x16_f16(a, b, acc, 0, 0, 0);
    }
#pragma unroll
    for (int r = 0; r < 16; ++r) {
        int m = mi * 32 + (r & 3) + 8 * (r >> 2) + 4 * q;
        rP[(ki * 32 + t) * 64 + m] = acc[r];
    }
    __syncthreads();
#pragma unroll
    for (int it = 0; it < 2; ++it) {
        int idx4 = (it * 256 + tid) * 4;
        int n = idx4 >> 6, o = idx4 & 63;
        f32x4 v0 = *(const f32x4*)(rP + n * 64 + o);
        f32x4 v1 = *(const f32x4*)(rP + (32 + n) * 64 + o);
        f32x4 bb = *(const f32x4*)(biasp + o);
        f32x4 ov;
        ov[0] = v0[0] + v1[0] + 64.0f * bb[0];
        ov[1] = v0[1] + v1[1] + 64.0f * bb[1];
        ov[2] = v0[2] + v1[2] + 64.0f * bb[2];
        ov[3] = v0[3] + v1[3] + 64.0f * bb[3];
        *(f32x4*)(out + (size_t)(bg * 32 + n) * 256 + colbase + o) = ov;
    }
}

__global__ void __launch_bounds__(256, 2)
cin_out(const f16* __restrict__ Wf, const f16* __restrict__ pW,
        const float* __restrict__ b0v, const float* __restrict__ b1v,
        const float* __restrict__ b2v, float* __restrict__ out)
{
    __shared__ __attribute__((aligned(16))) float rP[2 * 32 * 64];  // 16 KB
    const int tid = threadIdx.x;
    const int r  = blockIdx.x & 3;      // region
    const int bg = blockIdx.x >> 2;     // 32-batch group (64 of them)
    if (r == 0)
        o_tile<32>(Wf + 65536,  pW,        b0v + 64, out, rP, bg, 0,   tid);
    else if (r == 1)
        o_tile<64>(Wf + 262144, pW + 1024, b1v + 64, out, rP, bg, 64,  tid);
    else if (r == 2)
        o_tile<64>(Wf + 393216, pW + 3072, b2v,      out, rP, bg, 128, tid);
    else
        o_tile<64>(Wf + 524288, pW + 3072, b2v + 64, out, rP, bg, 192, tid);
}

extern "C" void kernel_launch(void* const* d_in, const int* in_sizes, int n_in,
                              void* d_out, int out_size, void* d_ws, size_t ws_size,
                              hipStream_t stream)
{
    const float* inp = (const float*)d_in[0];
    const float* W0  = (const float*)d_in[1];
    const float* b0  = (const float*)d_in[2];
    const float* W1  = (const float*)d_in[3];
    const float* b1  = (const float*)d_in[4];
    const float* W2  = (const float*)d_in[5];
    const float* b2  = (const float*)d_in[6];
    float* out = (float*)d_out;

    f16* Wf = (f16*)d_ws;             // 655360 f16 = 1.25 MB fragment-ordered
    f16* pW = Wf + 655360;            // 2048 * 5120 f16 = 20 MB p-vectors

    prep_frag<<<320, 256, 0, stream>>>(W0, W1, W2, Wf);
    cin_h<<<512, 256, 0, stream>>>(inp, Wf, pW, b0, b1);
    cin_out<<<256, 256, 0, stream>>>(Wf, pW, b0, b1, b2, out);
}